// Round 1
// baseline (1025.436 us; speedup 1.0000x reference)
//
#include <hip/hip_runtime.h>
#include <cstdint>
#include <cstddef>

#define L_C   2048
#define DIMC  5120
#define HD    128
#define NHEADS 40

typedef __bf16 bf16_t;
typedef __bf16 bf16x8 __attribute__((ext_vector_type(8)));
typedef __bf16 bf16x4 __attribute__((ext_vector_type(4)));
typedef float  f32x4  __attribute__((ext_vector_type(4)));

#define MFMA16(A,B,C) __builtin_amdgcn_mfma_f32_16x16x32_bf16((A),(B),(C),0,0,0)

__device__ __forceinline__ void gload16(const void* g, void* l) {
  __builtin_amdgcn_global_load_lds(
      (__attribute__((address_space(1))) void*)(void*)g,
      (__attribute__((address_space(3))) void*)l, 16, 0, 0);
}

// ---------------- f32 -> bf16 elementwise ----------------
__global__ __launch_bounds__(256) void f32_to_bf16(const float* __restrict__ in,
                                                   bf16_t* __restrict__ out, size_t n8) {
  size_t i = (size_t)blockIdx.x * blockDim.x + threadIdx.x;
  size_t stride = (size_t)gridDim.x * blockDim.x;
  for (; i < n8; i += stride) {
    f32x4 a = *(const f32x4*)(in + i * 8);
    f32x4 b = *(const f32x4*)(in + i * 8 + 4);
    bf16x8 o;
#pragma unroll
    for (int j = 0; j < 4; ++j) { o[j] = (bf16_t)a[j]; o[4 + j] = (bf16_t)b[j]; }
    *(bf16x8*)(out + i * 8) = o;
  }
}

// ------------- W [K][N] f32 -> Wt [N][K] bf16 (tiled transpose) -------------
__global__ __launch_bounds__(256) void wtrans(const float* __restrict__ W,
                                              bf16_t* __restrict__ Wt, int K, int N) {
  __shared__ bf16_t t[64][68];
  const int k0 = blockIdx.x * 64, n0 = blockIdx.y * 64, tid = threadIdx.x;
#pragma unroll
  for (int i = 0; i < 4; ++i) {
    int c = i * 256 + tid, rk = c >> 4, cn = (c & 15) * 4;
    f32x4 v = *(const f32x4*)(W + (size_t)(k0 + rk) * N + n0 + cn);
    bf16x4 o;
#pragma unroll
    for (int j = 0; j < 4; ++j) o[j] = (bf16_t)v[j];
    *(bf16x4*)&t[rk][cn] = o;
  }
  __syncthreads();
#pragma unroll
  for (int i = 0; i < 2; ++i) {
    int c = i * 256 + tid, rn = c >> 3, ck = (c & 7) * 8;
    bf16x8 v;
#pragma unroll
    for (int j = 0; j < 8; ++j) v[j] = t[ck + j][rn];
    *(bf16x8*)(Wt + (size_t)(n0 + rn) * K + k0 + ck) = v;
  }
}

// ------------- v slice of qkv -> Vt[h][d][l] (tiled transpose) -------------
__global__ __launch_bounds__(256) void v_trans(const bf16_t* __restrict__ qkv,
                                               bf16_t* __restrict__ Vt) {
  __shared__ bf16_t t[64][136];
  const int l0 = blockIdx.x * 64, h = blockIdx.y, tid = threadIdx.x;
#pragma unroll
  for (int i = 0; i < 4; ++i) {
    int c = i * 256 + tid, row = c >> 4, cb = c & 15;
    *(bf16x8*)&t[row][cb * 8] =
        *(const bf16x8*)(qkv + (size_t)(l0 + row) * (3 * DIMC) + 2 * DIMC + h * HD + cb * 8);
  }
  __syncthreads();
#pragma unroll
  for (int i = 0; i < 4; ++i) {
    int c = i * 256 + tid, d = c >> 3, lb = c & 7;
    bf16x8 v;
#pragma unroll
    for (int j = 0; j < 8; ++j) v[j] = t[lb * 8 + j][d];
    *(bf16x8*)(Vt + ((size_t)h * HD + d) * L_C + l0 + lb * 8) = v;
  }
}

// ---------------- GEMM: C = A(MxK) * Bt(NxK)^T + bias ----------------
// m97 structure: 128x128 tile, BK=32, 4 waves (2x2 of 64x64), global_load_lds w=16
template <int OUT_BF16>
__global__ __launch_bounds__(256, 2) void gemm_bt(const bf16_t* __restrict__ A,
                                                  const bf16_t* __restrict__ Bt,
                                                  const float* __restrict__ bias,
                                                  bf16_t* __restrict__ Cb,
                                                  float* __restrict__ Cf,
                                                  int M, int N, int K) {
  constexpr int BK = 32;
  __shared__ bf16_t la[2][128 * BK];
  __shared__ bf16_t lb[2][128 * BK];
  const int tid = threadIdx.x;
  const int wid = tid >> 6, lane = tid & 63, g = lane >> 4, r = lane & 15;
  // XCD-bijective swizzle (grid count % 8 == 0 for all our launches)
  const int nb = gridDim.x * gridDim.y;
  const int bid = blockIdx.y * gridDim.x + blockIdx.x;
  const int qq = nb >> 3;
  const int swz = (bid & 7) * qq + (bid >> 3);
  const int bm = swz % gridDim.x, bn = swz / gridDim.x;
  const int row0 = bm * 128, col0 = bn * 128;
  const int wm = (wid >> 1) * 64, wn = (wid & 1) * 64;
  f32x4 acc[4][4] = {};
  const int c0 = tid, c1 = tid + 256;

  auto stage = [&](int buf, int kt) {
    const size_t koff = (size_t)kt * BK;
    gload16(A + (size_t)(row0 + (c0 >> 2)) * K + koff + (c0 & 3) * 8,
            (char*)la[buf] + wid * 1024);
    gload16(A + (size_t)(row0 + (c1 >> 2)) * K + koff + (c1 & 3) * 8,
            (char*)la[buf] + wid * 1024 + 4096);
    gload16(Bt + (size_t)(col0 + (c0 >> 2)) * K + koff + (c0 & 3) * 8,
            (char*)lb[buf] + wid * 1024);
    gload16(Bt + (size_t)(col0 + (c1 >> 2)) * K + koff + (c1 & 3) * 8,
            (char*)lb[buf] + wid * 1024 + 4096);
  };

  stage(0, 0);
  __syncthreads();
  const int nk = K / BK;
  for (int kt = 0; kt < nk; ++kt) {
    const int cur = kt & 1;
    if (kt + 1 < nk) stage(cur ^ 1, kt + 1);
    bf16x8 af[4], bfr[4];
#pragma unroll
    for (int i = 0; i < 4; ++i) af[i] = *(const bf16x8*)&la[cur][(wm + i * 16 + r) * BK + g * 8];
#pragma unroll
    for (int j = 0; j < 4; ++j) bfr[j] = *(const bf16x8*)&lb[cur][(wn + j * 16 + r) * BK + g * 8];
#pragma unroll
    for (int i = 0; i < 4; ++i)
#pragma unroll
      for (int j = 0; j < 4; ++j) acc[i][j] = MFMA16(af[i], bfr[j], acc[i][j]);
    __syncthreads();
  }
#pragma unroll
  for (int i = 0; i < 4; ++i)
#pragma unroll
    for (int j = 0; j < 4; ++j)
#pragma unroll
      for (int p = 0; p < 4; ++p) {
        const int rr = row0 + wm + i * 16 + 4 * g + p;
        const int cc = col0 + wn + j * 16 + r;
        const float v = acc[i][j][p] + bias[cc];
        if (OUT_BF16) Cb[(size_t)rr * N + cc] = (bf16_t)v;
        else          Cf[(size_t)rr * N + cc] = v;
      }
}

// ---------------- RMSNorm(q,k) + RoPE -> Q[h][l][d], K[h][l][d] ----------------
__global__ __launch_bounds__(256) void norm_rope(const bf16_t* __restrict__ qkv,
                                                 const float* __restrict__ wq,
                                                 const float* __restrict__ wk,
                                                 const float* __restrict__ fcos,
                                                 const float* __restrict__ fsin,
                                                 bf16_t* __restrict__ Qo,
                                                 bf16_t* __restrict__ Ko) {
  const int l = blockIdx.x, tid = threadIdx.x;
  const bf16_t* row = qkv + (size_t)l * (3 * DIMC);
  float sq = 0.f, sk = 0.f;
  for (int i = tid; i < DIMC / 8; i += 256) {
    bf16x8 a = *(const bf16x8*)(row + i * 8);
    bf16x8 b = *(const bf16x8*)(row + DIMC + i * 8);
#pragma unroll
    for (int j = 0; j < 8; ++j) {
      float x = (float)a[j]; sq += x * x;
      float y = (float)b[j]; sk += y * y;
    }
  }
#pragma unroll
  for (int off = 32; off; off >>= 1) {
    sq += __shfl_xor(sq, off, 64);
    sk += __shfl_xor(sk, off, 64);
  }
  __shared__ float red[2][4];
  const int wid = tid >> 6, lane = tid & 63;
  if (!lane) { red[0][wid] = sq; red[1][wid] = sk; }
  __syncthreads();
  sq = red[0][0] + red[0][1] + red[0][2] + red[0][3];
  sk = red[1][0] + red[1][1] + red[1][2] + red[1][3];
  const float rq = rsqrtf(sq * (1.f / DIMC) + 1e-6f);
  const float rk = rsqrtf(sk * (1.f / DIMC) + 1e-6f);
  for (int i = tid; i < DIMC / 8; i += 256) {
    const int j0 = i * 8, h = j0 >> 7, d0 = j0 & 127;
    bf16x8 a = *(const bf16x8*)(row + j0);
    bf16x8 b = *(const bf16x8*)(row + DIMC + j0);
    f32x4 cA = *(const f32x4*)(fcos + (size_t)l * HD + d0);
    f32x4 cB = *(const f32x4*)(fcos + (size_t)l * HD + d0 + 4);
    f32x4 sA = *(const f32x4*)(fsin + (size_t)l * HD + d0);
    f32x4 sB = *(const f32x4*)(fsin + (size_t)l * HD + d0 + 4);
    f32x4 wqA = *(const f32x4*)(wq + j0), wqB = *(const f32x4*)(wq + j0 + 4);
    f32x4 wkA = *(const f32x4*)(wk + j0), wkB = *(const f32x4*)(wk + j0 + 4);
    float cc[8], ss[8], qn[8], kn[8];
#pragma unroll
    for (int j = 0; j < 4; ++j) {
      cc[j] = cA[j]; cc[4 + j] = cB[j];
      ss[j] = sA[j]; ss[4 + j] = sB[j];
      qn[j] = (float)a[j] * rq * wqA[j];
      qn[4 + j] = (float)a[4 + j] * rq * wqB[j];
      kn[j] = (float)b[j] * rk * wkA[j];
      kn[4 + j] = (float)b[4 + j] * rk * wkB[j];
    }
    bf16x8 oq, ok;
#pragma unroll
    for (int p = 0; p < 4; ++p) {
      const float c = cc[2 * p], s = ss[2 * p + 1];
      oq[2 * p]     = (bf16_t)(qn[2 * p] * c - qn[2 * p + 1] * s);
      oq[2 * p + 1] = (bf16_t)(qn[2 * p] * s + qn[2 * p + 1] * c);
      ok[2 * p]     = (bf16_t)(kn[2 * p] * c - kn[2 * p + 1] * s);
      ok[2 * p + 1] = (bf16_t)(kn[2 * p] * s + kn[2 * p + 1] * c);
    }
    *(bf16x8*)(Qo + ((size_t)h * L_C + l) * HD + d0) = oq;
    *(bf16x8*)(Ko + ((size_t)h * L_C + l) * HD + d0) = ok;
  }
}

// ---------------- flash attention: per (head, 64 q rows) ----------------
__global__ __launch_bounds__(256, 2) void attn(const bf16_t* __restrict__ Q,
                                               const bf16_t* __restrict__ Kg,
                                               const bf16_t* __restrict__ Vt,
                                               bf16_t* __restrict__ O) {
  __shared__ bf16_t k_lds[64 * HD];   // [key][d], XOR-swizzled
  __shared__ bf16_t v_lds[HD * 64];   // [d][key], XOR-swizzled
  __shared__ bf16_t p_lds[4][16 * 72];
  const int tid = threadIdx.x, wid = tid >> 6, lane = tid & 63;
  const int g = lane >> 4, r = lane & 15;
  const int h = blockIdx.y;
  const int q0 = blockIdx.x * 64 + wid * 16;
  bf16x8 qf[4];
  {
    const bf16_t* qrow = Q + ((size_t)h * L_C + q0 + r) * HD;
#pragma unroll
    for (int ks = 0; ks < 4; ++ks) qf[ks] = *(const bf16x8*)(qrow + ks * 32 + g * 8);
  }
  f32x4 oacc[8] = {};
  float m_i[4], l_i[4];
#pragma unroll
  for (int p = 0; p < 4; ++p) { m_i[p] = -1e30f; l_i[p] = 0.f; }
  const float scale = 0.08838834764831845f;  // 1/sqrt(128)

  for (int kv0 = 0; kv0 < L_C; kv0 += 64) {
#pragma unroll
    for (int i = 0; i < 4; ++i) {
      const int c = i * 256 + tid;
      const int krow = c >> 4, kcb = c & 15;
      bf16x8 tk = *(const bf16x8*)(Kg + ((size_t)h * L_C + kv0 + krow) * HD + kcb * 8);
      *(bf16x8*)((char*)k_lds + krow * 256 + ((kcb * 16) ^ ((krow & 7) << 4))) = tk;
      const int vrow = c >> 3, vcb = c & 7;
      bf16x8 tv = *(const bf16x8*)(Vt + ((size_t)h * HD + vrow) * L_C + kv0 + vcb * 8);
      *(bf16x8*)((char*)v_lds + vrow * 128 + ((vcb * 16) ^ ((vrow & 7) << 4))) = tv;
    }
    __syncthreads();
    // QK^T
    float pv[4][4];
#pragma unroll
    for (int nf = 0; nf < 4; ++nf) {
      f32x4 sacc = {0.f, 0.f, 0.f, 0.f};
      const int key = nf * 16 + r;
#pragma unroll
      for (int ks = 0; ks < 4; ++ks) {
        bf16x8 kf = *(const bf16x8*)((const char*)k_lds + key * 256 +
                                     ((ks * 64 + g * 16) ^ ((key & 7) << 4)));
        sacc = MFMA16(qf[ks], kf, sacc);
      }
#pragma unroll
      for (int p = 0; p < 4; ++p) pv[nf][p] = sacc[p] * scale;
    }
    // online softmax (row lives across 16 lanes of the lane&15 group)
    float mnew[4];
#pragma unroll
    for (int p = 0; p < 4; ++p)
      mnew[p] = fmaxf(fmaxf(pv[0][p], pv[1][p]), fmaxf(pv[2][p], pv[3][p]));
#pragma unroll
    for (int m = 1; m < 16; m <<= 1)
#pragma unroll
      for (int p = 0; p < 4; ++p) mnew[p] = fmaxf(mnew[p], __shfl_xor(mnew[p], m, 64));
    float alpha[4], rsum[4];
#pragma unroll
    for (int p = 0; p < 4; ++p) {
      const float mi = fmaxf(m_i[p], mnew[p]);
      alpha[p] = __expf(m_i[p] - mi);
      m_i[p] = mi;
      rsum[p] = 0.f;
    }
#pragma unroll
    for (int nf = 0; nf < 4; ++nf)
#pragma unroll
      for (int p = 0; p < 4; ++p) {
        pv[nf][p] = __expf(pv[nf][p] - m_i[p]);
        rsum[p] += pv[nf][p];
      }
#pragma unroll
    for (int nf = 0; nf < 4; ++nf)
#pragma unroll
      for (int p = 0; p < 4; ++p)
        p_lds[wid][(4 * g + p) * 72 + nf * 16 + r] = (bf16_t)pv[nf][p];
#pragma unroll
    for (int m = 1; m < 16; m <<= 1)
#pragma unroll
      for (int p = 0; p < 4; ++p) rsum[p] += __shfl_xor(rsum[p], m, 64);
#pragma unroll
    for (int p = 0; p < 4; ++p) l_i[p] = l_i[p] * alpha[p] + rsum[p];
#pragma unroll
    for (int nf = 0; nf < 8; ++nf)
#pragma unroll
      for (int p = 0; p < 4; ++p) oacc[nf][p] *= alpha[p];
    // PV
    bf16x8 pf0 = *(const bf16x8*)&p_lds[wid][r * 72 + 8 * g];
    bf16x8 pf1 = *(const bf16x8*)&p_lds[wid][r * 72 + 32 + 8 * g];
#pragma unroll
    for (int nf = 0; nf < 8; ++nf) {
      const int d = nf * 16 + r;
      bf16x8 vf0 = *(const bf16x8*)((const char*)v_lds + d * 128 +
                                    ((g * 16) ^ ((d & 7) << 4)));
      oacc[nf] = MFMA16(pf0, vf0, oacc[nf]);
      bf16x8 vf1 = *(const bf16x8*)((const char*)v_lds + d * 128 +
                                    ((64 + g * 16) ^ ((d & 7) << 4)));
      oacc[nf] = MFMA16(pf1, vf1, oacc[nf]);
    }
    __syncthreads();
  }
#pragma unroll
  for (int p = 0; p < 4; ++p) {
    const float inv = 1.f / l_i[p];
    const int rowg = q0 + 4 * g + p;
#pragma unroll
    for (int nf = 0; nf < 8; ++nf) {
      const int d = nf * 16 + r;
      O[(size_t)rowg * DIMC + h * HD + d] = (bf16_t)(oacc[nf][p] * inv);
    }
  }
}

// ---------------- launch ----------------
extern "C" void kernel_launch(void* const* d_in, const int* in_sizes, int n_in,
                              void* d_out, int out_size, void* d_ws, size_t ws_size,
                              hipStream_t stream) {
  const float* hidden = (const float*)d_in[0];
  const float* fcos   = (const float*)d_in[1];
  const float* fsin   = (const float*)d_in[2];
  const float* Wqkv   = (const float*)d_in[3];
  const float* bqkv   = (const float*)d_in[4];
  const float* wnq    = (const float*)d_in[5];
  const float* wnk    = (const float*)d_in[6];
  const float* Wout   = (const float*)d_in[7];
  const float* bout   = (const float*)d_in[8];
  float* out = (float*)d_out;

  char* ws = (char*)d_ws;
  size_t off = 0;
  auto alloc = [&](size_t bytes) {
    void* p = ws + off;
    off += (bytes + 255) & ~(size_t)255;
    return p;
  };
  bf16_t* X   = (bf16_t*)alloc((size_t)L_C * DIMC * 2);
  bf16_t* WQT = (bf16_t*)alloc((size_t)3 * DIMC * DIMC * 2);
  bf16_t* WOT = (bf16_t*)alloc((size_t)DIMC * DIMC * 2);
  bf16_t* QKV = (bf16_t*)alloc((size_t)L_C * 3 * DIMC * 2);
  bf16_t* Qb  = (bf16_t*)alloc((size_t)L_C * DIMC * 2);
  bf16_t* Kb  = (bf16_t*)alloc((size_t)L_C * DIMC * 2);
  bf16_t* VT  = (bf16_t*)alloc((size_t)L_C * DIMC * 2);
  bf16_t* Ob  = X;  // X dead after gemm1; reuse for attention output

  f32_to_bf16<<<2048, 256, 0, stream>>>(hidden, X, (size_t)L_C * DIMC / 8);
  wtrans<<<dim3(DIMC / 64, 3 * DIMC / 64), 256, 0, stream>>>(Wqkv, WQT, DIMC, 3 * DIMC);
  wtrans<<<dim3(DIMC / 64, DIMC / 64), 256, 0, stream>>>(Wout, WOT, DIMC, DIMC);
  gemm_bt<1><<<dim3(L_C / 128, 3 * DIMC / 128), 256, 0, stream>>>(
      X, WQT, bqkv, QKV, nullptr, L_C, 3 * DIMC, DIMC);
  norm_rope<<<L_C, 256, 0, stream>>>(QKV, wnq, wnk, fcos, fsin, Qb, Kb);
  v_trans<<<dim3(L_C / 64, NHEADS), 256, 0, stream>>>(QKV, VT);
  attn<<<dim3(L_C / 64, NHEADS), 256, 0, stream>>>(Qb, Kb, VT, Ob);
  gemm_bt<0><<<dim3(L_C / 128, DIMC / 128), 256, 0, stream>>>(
      Ob, WOT, bout, nullptr, out, L_C, DIMC, DIMC);
}

// Round 3
// 882.466 us; speedup vs baseline: 1.1620x; 1.1620x over previous
//
#include <hip/hip_runtime.h>
#include <cstdint>
#include <cstddef>

#define L_C   2048
#define DIMC  5120
#define HD    128
#define NHEADS 40

typedef __bf16 bf16_t;
typedef __bf16 bf16x8 __attribute__((ext_vector_type(8)));
typedef __bf16 bf16x4 __attribute__((ext_vector_type(4)));
typedef float  f32x4  __attribute__((ext_vector_type(4)));

#define MFMA16(A,B,C) __builtin_amdgcn_mfma_f32_16x16x32_bf16((A),(B),(C),0,0,0)
#define BARRIER() __builtin_amdgcn_s_barrier()
#define VMCNT0() asm volatile("s_waitcnt vmcnt(0)" ::: "memory")

__device__ __forceinline__ void gload16(const void* g, void* l) {
  __builtin_amdgcn_global_load_lds(
      (__attribute__((address_space(1))) void*)(void*)g,
      (__attribute__((address_space(3))) void*)l, 16, 0, 0);
}

// ---------------- f32 -> bf16 elementwise ----------------
__global__ __launch_bounds__(256) void f32_to_bf16(const float* __restrict__ in,
                                                   bf16_t* __restrict__ out, size_t n8) {
  size_t i = (size_t)blockIdx.x * blockDim.x + threadIdx.x;
  size_t stride = (size_t)gridDim.x * blockDim.x;
  for (; i < n8; i += stride) {
    f32x4 a = *(const f32x4*)(in + i * 8);
    f32x4 b = *(const f32x4*)(in + i * 8 + 4);
    bf16x8 o;
#pragma unroll
    for (int j = 0; j < 4; ++j) { o[j] = (bf16_t)a[j]; o[4 + j] = (bf16_t)b[j]; }
    *(bf16x8*)(out + i * 8) = o;
  }
}

// ------------- W [K][N] f32 -> Wt [N][K] bf16 (tiled transpose) -------------
__global__ __launch_bounds__(256) void wtrans(const float* __restrict__ W,
                                              bf16_t* __restrict__ Wt, int K, int N) {
  __shared__ bf16_t t[64][68];
  const int k0 = blockIdx.x * 64, n0 = blockIdx.y * 64, tid = threadIdx.x;
#pragma unroll
  for (int i = 0; i < 4; ++i) {
    int c = i * 256 + tid, rk = c >> 4, cn = (c & 15) * 4;
    f32x4 v = *(const f32x4*)(W + (size_t)(k0 + rk) * N + n0 + cn);
    bf16x4 o;
#pragma unroll
    for (int j = 0; j < 4; ++j) o[j] = (bf16_t)v[j];
    *(bf16x4*)&t[rk][cn] = o;
  }
  __syncthreads();
#pragma unroll
  for (int i = 0; i < 2; ++i) {
    int c = i * 256 + tid, rn = c >> 3, ck = (c & 7) * 8;
    bf16x8 v;
#pragma unroll
    for (int j = 0; j < 8; ++j) v[j] = t[ck + j][rn];
    *(bf16x8*)(Wt + (size_t)(n0 + rn) * K + k0 + ck) = v;
  }
}

// ------------- v slice of qkv -> Vt[h][d][l] (tiled transpose) -------------
__global__ __launch_bounds__(256) void v_trans(const bf16_t* __restrict__ qkv,
                                               bf16_t* __restrict__ Vt) {
  __shared__ bf16_t t[64][136];
  const int l0 = blockIdx.x * 64, h = blockIdx.y, tid = threadIdx.x;
#pragma unroll
  for (int i = 0; i < 4; ++i) {
    int c = i * 256 + tid, row = c >> 4, cb = c & 15;
    *(bf16x8*)&t[row][cb * 8] =
        *(const bf16x8*)(qkv + (size_t)(l0 + row) * (3 * DIMC) + 2 * DIMC + h * HD + cb * 8);
  }
  __syncthreads();
#pragma unroll
  for (int i = 0; i < 4; ++i) {
    int c = i * 256 + tid, d = c >> 3, lb = c & 7;
    bf16x8 v;
#pragma unroll
    for (int j = 0; j < 8; ++j) v[j] = t[lb * 8 + j][d];
    *(bf16x8*)(Vt + ((size_t)h * HD + d) * L_C + l0 + lb * 8) = v;
  }
}

// ================= 256x256 4-phase GEMM: C = A(MxK) * Bt(NxK)^T + bias =================
// 8 waves (2M x 4N), per-wave C = 128x64, BK=64, 2 LDS buffers of (A 32KB + B 32KB).
// RACE-FREE INVARIANT: during tile k all staging targets buf (k+1)&1 only (never the
// buffer being read). Tile k+1's 8 gload_lds/thread issue in phases 1-2; a single
// vmcnt(0)+barrier at the tile boundary covers RAW; WAR is free (buf^1's old content
// was fully consumed before tile k-1's closing barrier).
// LDS swizzle: linear dest (gload_lds requirement) + inverse-swizzled GLOBAL source
// + same-involution ds_read: chunk c of row r holds global chunk c ^ (r&7).
template <int OUT_BF16, int K>
__global__ __launch_bounds__(512, 1) void gemm8(const bf16_t* __restrict__ A,
                                                const bf16_t* __restrict__ Bt,
                                                const float* __restrict__ bias,
                                                bf16_t* __restrict__ Cb,
                                                float* __restrict__ Cf,
                                                int M, int N) {
  __shared__ __align__(16) char smem[131072];
  const int tid = threadIdx.x;
  const int wid = tid >> 6, lane = tid & 63;
  const int g = lane >> 4, r = lane & 15;
  const int wm = wid >> 2, wn = wid & 3;
  // XCD-bijective swizzle (grid count % 8 == 0 for all our launches)
  const int nb = gridDim.x * gridDim.y;
  const int bid = blockIdx.y * gridDim.x + blockIdx.x;
  const int swz = (bid & 7) * (nb >> 3) + (bid >> 3);
  const int bm = swz % gridDim.x, bn = swz / gridDim.x;
  const int row0 = bm * 256, col0 = bn * 256;

  auto stageA = [&](int buf, int half, int kt) {
#pragma unroll
    for (int i = 0; i < 2; ++i) {
      const int idx = i * 512 + tid;
      const int rl = idx >> 3, c = idx & 7;
      gload16(A + (size_t)(row0 + half * 128 + rl) * K + kt * 64 + ((c ^ (rl & 7)) << 3),
              smem + buf * 65536 + half * 16384 + (i * 512 + wid * 64) * 16);
    }
  };
  auto stageB = [&](int buf, int half, int kt) {
#pragma unroll
    for (int i = 0; i < 2; ++i) {
      const int idx = i * 512 + tid;
      const int rl = idx >> 3, c = idx & 7;
      gload16(Bt + (size_t)(col0 + half * 128 + rl) * K + kt * 64 + ((c ^ (rl & 7)) << 3),
              smem + buf * 65536 + 32768 + half * 16384 + (i * 512 + wid * 64) * 16);
    }
  };
  auto ldA = [&](int buf, int mi, int kk) {
    const int rh = mi * 16 + r;  // 0..127 within wave's half (wm)
    return *(const bf16x8*)(smem + buf * 65536 + wm * 16384 + rh * 128 +
                            (((kk * 4 + g) ^ (r & 7)) << 4));
  };
  auto ldB = [&](int buf, int ni, int kk) {
    const int rh = (wn & 1) * 64 + ni * 16 + r;  // 0..127 within half (wn>>1)
    return *(const bf16x8*)(smem + buf * 65536 + 32768 + (wn >> 1) * 16384 + rh * 128 +
                            (((kk * 4 + g) ^ (r & 7)) << 4));
  };

  f32x4 acc[8][4] = {};
  bf16x8 af[4][2], bfr[2][2];
  constexpr int nk = K / 64;

  // Prologue: tile 0 -> buf0, wait, sync.
  stageA(0, 0, 0); stageA(0, 1, 0); stageB(0, 0, 0); stageB(0, 1, 0);
  VMCNT0();
  BARRIER();

  auto ktile = [&](int k, int cur) {
    const bool pf = (k + 1 < nk);
    // ---- phase 1: read A mi0-3 + B ni0-1 of buf cur; stage A(k+1) -> buf^1
#pragma unroll
    for (int i = 0; i < 4; ++i)
#pragma unroll
      for (int kk = 0; kk < 2; ++kk) af[i][kk] = ldA(cur, i, kk);
#pragma unroll
    for (int j = 0; j < 2; ++j)
#pragma unroll
      for (int kk = 0; kk < 2; ++kk) bfr[j][kk] = ldB(cur, j, kk);
    if (pf) { stageA(cur ^ 1, 0, k + 1); stageA(cur ^ 1, 1, k + 1); }
    BARRIER();
    __builtin_amdgcn_s_setprio(1);
#pragma unroll
    for (int i = 0; i < 4; ++i)
#pragma unroll
      for (int j = 0; j < 2; ++j)
#pragma unroll
        for (int kk = 0; kk < 2; ++kk)
          acc[i][j] = MFMA16(af[i][kk], bfr[j][kk], acc[i][j]);
    __builtin_amdgcn_s_setprio(0);
    BARRIER();
    // ---- phase 2: read A mi4-7; stage B(k+1) -> buf^1
#pragma unroll
    for (int i = 0; i < 4; ++i)
#pragma unroll
      for (int kk = 0; kk < 2; ++kk) af[i][kk] = ldA(cur, 4 + i, kk);
    if (pf) { stageB(cur ^ 1, 0, k + 1); stageB(cur ^ 1, 1, k + 1); }
    BARRIER();
    __builtin_amdgcn_s_setprio(1);
#pragma unroll
    for (int i = 0; i < 4; ++i)
#pragma unroll
      for (int j = 0; j < 2; ++j)
#pragma unroll
        for (int kk = 0; kk < 2; ++kk)
          acc[4 + i][j] = MFMA16(af[i][kk], bfr[j][kk], acc[4 + i][j]);
    __builtin_amdgcn_s_setprio(0);
    BARRIER();
    // ---- phase 3: read B ni2-3 (af mi4-7 still live)
#pragma unroll
    for (int j = 0; j < 2; ++j)
#pragma unroll
      for (int kk = 0; kk < 2; ++kk) bfr[j][kk] = ldB(cur, 2 + j, kk);
    BARRIER();
    __builtin_amdgcn_s_setprio(1);
#pragma unroll
    for (int i = 0; i < 4; ++i)
#pragma unroll
      for (int j = 0; j < 2; ++j)
#pragma unroll
        for (int kk = 0; kk < 2; ++kk)
          acc[4 + i][2 + j] = MFMA16(af[i][kk], bfr[j][kk], acc[4 + i][2 + j]);
    __builtin_amdgcn_s_setprio(0);
    BARRIER();
    // ---- phase 4: re-read A mi0-3 (bfr ni2-3 still live); tile-boundary drain
#pragma unroll
    for (int i = 0; i < 4; ++i)
#pragma unroll
      for (int kk = 0; kk < 2; ++kk) af[i][kk] = ldA(cur, i, kk);
    BARRIER();
    __builtin_amdgcn_s_setprio(1);
#pragma unroll
    for (int i = 0; i < 4; ++i)
#pragma unroll
      for (int j = 0; j < 2; ++j)
#pragma unroll
        for (int kk = 0; kk < 2; ++kk)
          acc[i][2 + j] = MFMA16(af[i][kk], bfr[j][kk], acc[i][2 + j]);
    __builtin_amdgcn_s_setprio(0);
    VMCNT0();   // tile k+1's 8 staging ops (issued 2-3 phases ago) -> landed
    BARRIER();  // all waves' stages visible before buffer swap
  };

  for (int kp = 0; kp < nk; kp += 2) { ktile(kp, 0); ktile(kp + 1, 1); }

  // Epilogue
#pragma unroll
  for (int mi = 0; mi < 8; ++mi)
#pragma unroll
    for (int ni = 0; ni < 4; ++ni)
#pragma unroll
      for (int p = 0; p < 4; ++p) {
        const int rr = row0 + wm * 128 + mi * 16 + 4 * g + p;
        const int cc = col0 + wn * 64 + ni * 16 + r;
        const float v = acc[mi][ni][p] + bias[cc];
        if (OUT_BF16) Cb[(size_t)rr * N + cc] = (bf16_t)v;
        else          Cf[(size_t)rr * N + cc] = v;
      }
}

// ---------------- RMSNorm(q,k) + RoPE -> Q[h][l][d], K[h][l][d] ----------------
__global__ __launch_bounds__(256) void norm_rope(const bf16_t* __restrict__ qkv,
                                                 const float* __restrict__ wq,
                                                 const float* __restrict__ wk,
                                                 const float* __restrict__ fcos,
                                                 const float* __restrict__ fsin,
                                                 bf16_t* __restrict__ Qo,
                                                 bf16_t* __restrict__ Ko) {
  const int l = blockIdx.x, tid = threadIdx.x;
  const bf16_t* row = qkv + (size_t)l * (3 * DIMC);
  float sq = 0.f, sk = 0.f;
  for (int i = tid; i < DIMC / 8; i += 256) {
    bf16x8 a = *(const bf16x8*)(row + i * 8);
    bf16x8 b = *(const bf16x8*)(row + DIMC + i * 8);
#pragma unroll
    for (int j = 0; j < 8; ++j) {
      float x = (float)a[j]; sq += x * x;
      float y = (float)b[j]; sk += y * y;
    }
  }
#pragma unroll
  for (int off = 32; off; off >>= 1) {
    sq += __shfl_xor(sq, off, 64);
    sk += __shfl_xor(sk, off, 64);
  }
  __shared__ float red[2][4];
  const int wid = tid >> 6, lane = tid & 63;
  if (!lane) { red[0][wid] = sq; red[1][wid] = sk; }
  __syncthreads();
  sq = red[0][0] + red[0][1] + red[0][2] + red[0][3];
  sk = red[1][0] + red[1][1] + red[1][2] + red[1][3];
  const float rq = rsqrtf(sq * (1.f / DIMC) + 1e-6f);
  const float rk = rsqrtf(sk * (1.f / DIMC) + 1e-6f);
  for (int i = tid; i < DIMC / 8; i += 256) {
    const int j0 = i * 8, h = j0 >> 7, d0 = j0 & 127;
    bf16x8 a = *(const bf16x8*)(row + j0);
    bf16x8 b = *(const bf16x8*)(row + DIMC + j0);
    f32x4 cA = *(const f32x4*)(fcos + (size_t)l * HD + d0);
    f32x4 cB = *(const f32x4*)(fcos + (size_t)l * HD + d0 + 4);
    f32x4 sA = *(const f32x4*)(fsin + (size_t)l * HD + d0);
    f32x4 sB = *(const f32x4*)(fsin + (size_t)l * HD + d0 + 4);
    f32x4 wqA = *(const f32x4*)(wq + j0), wqB = *(const f32x4*)(wq + j0 + 4);
    f32x4 wkA = *(const f32x4*)(wk + j0), wkB = *(const f32x4*)(wk + j0 + 4);
    float cc[8], ss[8], qn[8], kn[8];
#pragma unroll
    for (int j = 0; j < 4; ++j) {
      cc[j] = cA[j]; cc[4 + j] = cB[j];
      ss[j] = sA[j]; ss[4 + j] = sB[j];
      qn[j] = (float)a[j] * rq * wqA[j];
      qn[4 + j] = (float)a[4 + j] * rq * wqB[j];
      kn[j] = (float)b[j] * rk * wkA[j];
      kn[4 + j] = (float)b[4 + j] * rk * wkB[j];
    }
    bf16x8 oq, ok;
#pragma unroll
    for (int p = 0; p < 4; ++p) {
      const float c = cc[2 * p], s = ss[2 * p + 1];
      oq[2 * p]     = (bf16_t)(qn[2 * p] * c - qn[2 * p + 1] * s);
      oq[2 * p + 1] = (bf16_t)(qn[2 * p] * s + qn[2 * p + 1] * c);
      ok[2 * p]     = (bf16_t)(kn[2 * p] * c - kn[2 * p + 1] * s);
      ok[2 * p + 1] = (bf16_t)(kn[2 * p] * s + kn[2 * p + 1] * c);
    }
    *(bf16x8*)(Qo + ((size_t)h * L_C + l) * HD + d0) = oq;
    *(bf16x8*)(Ko + ((size_t)h * L_C + l) * HD + d0) = ok;
  }
}

// ---------------- flash attention: per (head, 64 q rows) ----------------
__global__ __launch_bounds__(256, 2) void attn(const bf16_t* __restrict__ Q,
                                               const bf16_t* __restrict__ Kg,
                                               const bf16_t* __restrict__ Vt,
                                               bf16_t* __restrict__ O) {
  __shared__ bf16_t k_lds[64 * HD];   // [key][d], XOR-swizzled
  __shared__ bf16_t v_lds[HD * 64];   // [d][key], XOR-swizzled
  __shared__ bf16_t p_lds[4][16 * 72];
  const int tid = threadIdx.x, wid = tid >> 6, lane = tid & 63;
  const int g = lane >> 4, r = lane & 15;
  const int h = blockIdx.y;
  const int q0 = blockIdx.x * 64 + wid * 16;
  bf16x8 qf[4];
  {
    const bf16_t* qrow = Q + ((size_t)h * L_C + q0 + r) * HD;
#pragma unroll
    for (int ks = 0; ks < 4; ++ks) qf[ks] = *(const bf16x8*)(qrow + ks * 32 + g * 8);
  }
  f32x4 oacc[8] = {};
  float m_i[4], l_i[4];
#pragma unroll
  for (int p = 0; p < 4; ++p) { m_i[p] = -1e30f; l_i[p] = 0.f; }
  const float scale = 0.08838834764831845f;  // 1/sqrt(128)

  for (int kv0 = 0; kv0 < L_C; kv0 += 64) {
#pragma unroll
    for (int i = 0; i < 4; ++i) {
      const int c = i * 256 + tid;
      const int krow = c >> 4, kcb = c & 15;
      bf16x8 tk = *(const bf16x8*)(Kg + ((size_t)h * L_C + kv0 + krow) * HD + kcb * 8);
      *(bf16x8*)((char*)k_lds + krow * 256 + ((kcb * 16) ^ ((krow & 7) << 4))) = tk;
      const int vrow = c >> 3, vcb = c & 7;
      bf16x8 tv = *(const bf16x8*)(Vt + ((size_t)h * HD + vrow) * L_C + kv0 + vcb * 8);
      *(bf16x8*)((char*)v_lds + vrow * 128 + ((vcb * 16) ^ ((vrow & 7) << 4))) = tv;
    }
    __syncthreads();
    // QK^T
    float pv[4][4];
#pragma unroll
    for (int nf = 0; nf < 4; ++nf) {
      f32x4 sacc = {0.f, 0.f, 0.f, 0.f};
      const int key = nf * 16 + r;
#pragma unroll
      for (int ks = 0; ks < 4; ++ks) {
        bf16x8 kf = *(const bf16x8*)((const char*)k_lds + key * 256 +
                                     ((ks * 64 + g * 16) ^ ((key & 7) << 4)));
        sacc = MFMA16(qf[ks], kf, sacc);
      }
#pragma unroll
      for (int p = 0; p < 4; ++p) pv[nf][p] = sacc[p] * scale;
    }
    // online softmax (row lives across 16 lanes of the lane&15 group)
    float mnew[4];
#pragma unroll
    for (int p = 0; p < 4; ++p)
      mnew[p] = fmaxf(fmaxf(pv[0][p], pv[1][p]), fmaxf(pv[2][p], pv[3][p]));
#pragma unroll
    for (int m = 1; m < 16; m <<= 1)
#pragma unroll
      for (int p = 0; p < 4; ++p) mnew[p] = fmaxf(mnew[p], __shfl_xor(mnew[p], m, 64));
    float alpha[4], rsum[4];
#pragma unroll
    for (int p = 0; p < 4; ++p) {
      const float mi = fmaxf(m_i[p], mnew[p]);
      alpha[p] = __expf(m_i[p] - mi);
      m_i[p] = mi;
      rsum[p] = 0.f;
    }
#pragma unroll
    for (int nf = 0; nf < 4; ++nf)
#pragma unroll
      for (int p = 0; p < 4; ++p) {
        pv[nf][p] = __expf(pv[nf][p] - m_i[p]);
        rsum[p] += pv[nf][p];
      }
#pragma unroll
    for (int nf = 0; nf < 4; ++nf)
#pragma unroll
      for (int p = 0; p < 4; ++p)
        p_lds[wid][(4 * g + p) * 72 + nf * 16 + r] = (bf16_t)pv[nf][p];
#pragma unroll
    for (int m = 1; m < 16; m <<= 1)
#pragma unroll
      for (int p = 0; p < 4; ++p) rsum[p] += __shfl_xor(rsum[p], m, 64);
#pragma unroll
    for (int p = 0; p < 4; ++p) l_i[p] = l_i[p] * alpha[p] + rsum[p];
#pragma unroll
    for (int nf = 0; nf < 8; ++nf)
#pragma unroll
      for (int p = 0; p < 4; ++p) oacc[nf][p] *= alpha[p];
    // PV
    bf16x8 pf0 = *(const bf16x8*)&p_lds[wid][r * 72 + 8 * g];
    bf16x8 pf1 = *(const bf16x8*)&p_lds[wid][r * 72 + 32 + 8 * g];
#pragma unroll
    for (int nf = 0; nf < 8; ++nf) {
      const int d = nf * 16 + r;
      bf16x8 vf0 = *(const bf16x8*)((const char*)v_lds + d * 128 +
                                    ((g * 16) ^ ((d & 7) << 4)));
      oacc[nf] = MFMA16(pf0, vf0, oacc[nf]);
      bf16x8 vf1 = *(const bf16x8*)((const char*)v_lds + d * 128 +
                                    ((64 + g * 16) ^ ((d & 7) << 4)));
      oacc[nf] = MFMA16(pf1, vf1, oacc[nf]);
    }
    __syncthreads();
  }
#pragma unroll
  for (int p = 0; p < 4; ++p) {
    const float inv = 1.f / l_i[p];
    const int rowg = q0 + 4 * g + p;
#pragma unroll
    for (int nf = 0; nf < 8; ++nf) {
      const int d = nf * 16 + r;
      O[(size_t)rowg * DIMC + h * HD + d] = (bf16_t)(oacc[nf][p] * inv);
    }
  }
}

// ---------------- launch ----------------
extern "C" void kernel_launch(void* const* d_in, const int* in_sizes, int n_in,
                              void* d_out, int out_size, void* d_ws, size_t ws_size,
                              hipStream_t stream) {
  const float* hidden = (const float*)d_in[0];
  const float* fcos   = (const float*)d_in[1];
  const float* fsin   = (const float*)d_in[2];
  const float* Wqkv   = (const float*)d_in[3];
  const float* bqkv   = (const float*)d_in[4];
  const float* wnq    = (const float*)d_in[5];
  const float* wnk    = (const float*)d_in[6];
  const float* Wout   = (const float*)d_in[7];
  const float* bout   = (const float*)d_in[8];
  float* out = (float*)d_out;

  char* ws = (char*)d_ws;
  size_t off = 0;
  auto alloc = [&](size_t bytes) {
    void* p = ws + off;
    off += (bytes + 255) & ~(size_t)255;
    return p;
  };
  bf16_t* X   = (bf16_t*)alloc((size_t)L_C * DIMC * 2);
  bf16_t* WQT = (bf16_t*)alloc((size_t)3 * DIMC * DIMC * 2);
  bf16_t* WOT = (bf16_t*)alloc((size_t)DIMC * DIMC * 2);
  bf16_t* QKV = (bf16_t*)alloc((size_t)L_C * 3 * DIMC * 2);
  bf16_t* Qb  = (bf16_t*)alloc((size_t)L_C * DIMC * 2);
  bf16_t* Kb  = (bf16_t*)alloc((size_t)L_C * DIMC * 2);
  bf16_t* VT  = (bf16_t*)alloc((size_t)L_C * DIMC * 2);
  bf16_t* Ob  = X;  // X dead after gemm1; reuse for attention output

  f32_to_bf16<<<2048, 256, 0, stream>>>(hidden, X, (size_t)L_C * DIMC / 8);
  wtrans<<<dim3(DIMC / 64, 3 * DIMC / 64), 256, 0, stream>>>(Wqkv, WQT, DIMC, 3 * DIMC);
  wtrans<<<dim3(DIMC / 64, DIMC / 64), 256, 0, stream>>>(Wout, WOT, DIMC, DIMC);
  gemm8<1, DIMC><<<dim3(L_C / 256, 3 * DIMC / 256), 512, 0, stream>>>(
      X, WQT, bqkv, QKV, nullptr, L_C, 3 * DIMC);
  norm_rope<<<L_C, 256, 0, stream>>>(QKV, wnq, wnk, fcos, fsin, Qb, Kb);
  v_trans<<<dim3(L_C / 64, NHEADS), 256, 0, stream>>>(QKV, VT);
  attn<<<dim3(L_C / 64, NHEADS), 256, 0, stream>>>(Qb, Kb, VT, Ob);
  gemm8<0, DIMC><<<dim3(L_C / 256, DIMC / 256), 512, 0, stream>>>(
      Ob, WOT, bout, nullptr, out, L_C, DIMC);
}

// Round 4
// 815.901 us; speedup vs baseline: 1.2568x; 1.0816x over previous
//
#include <hip/hip_runtime.h>
#include <cstdint>
#include <cstddef>

#define L_C   2048
#define DIMC  5120
#define HD    128
#define NHEADS 40

typedef __bf16 bf16_t;
typedef __bf16 bf16x8 __attribute__((ext_vector_type(8)));
typedef __bf16 bf16x4 __attribute__((ext_vector_type(4)));
typedef float  f32x4  __attribute__((ext_vector_type(4)));

#define MFMA16(A,B,C) __builtin_amdgcn_mfma_f32_16x16x32_bf16((A),(B),(C),0,0,0)
#define BARRIER() __builtin_amdgcn_s_barrier()
#define VMCNT0() asm volatile("s_waitcnt vmcnt(0)" ::: "memory")

__device__ __forceinline__ void gload16(const void* g, void* l) {
  __builtin_amdgcn_global_load_lds(
      (__attribute__((address_space(1))) void*)(void*)g,
      (__attribute__((address_space(3))) void*)l, 16, 0, 0);
}

// ---------------- f32 -> bf16 elementwise ----------------
__global__ __launch_bounds__(256) void f32_to_bf16(const float* __restrict__ in,
                                                   bf16_t* __restrict__ out, size_t n8) {
  size_t i = (size_t)blockIdx.x * blockDim.x + threadIdx.x;
  size_t stride = (size_t)gridDim.x * blockDim.x;
  for (; i < n8; i += stride) {
    f32x4 a = *(const f32x4*)(in + i * 8);
    f32x4 b = *(const f32x4*)(in + i * 8 + 4);
    bf16x8 o;
#pragma unroll
    for (int j = 0; j < 4; ++j) { o[j] = (bf16_t)a[j]; o[4 + j] = (bf16_t)b[j]; }
    *(bf16x8*)(out + i * 8) = o;
  }
}

// ------------- W [K][N] f32 -> Wt [N][K] bf16 (tiled transpose) -------------
__global__ __launch_bounds__(256) void wtrans(const float* __restrict__ W,
                                              bf16_t* __restrict__ Wt, int K, int N) {
  __shared__ bf16_t t[64][68];
  const int k0 = blockIdx.x * 64, n0 = blockIdx.y * 64, tid = threadIdx.x;
#pragma unroll
  for (int i = 0; i < 4; ++i) {
    int c = i * 256 + tid, rk = c >> 4, cn = (c & 15) * 4;
    f32x4 v = *(const f32x4*)(W + (size_t)(k0 + rk) * N + n0 + cn);
    bf16x4 o;
#pragma unroll
    for (int j = 0; j < 4; ++j) o[j] = (bf16_t)v[j];
    *(bf16x4*)&t[rk][cn] = o;
  }
  __syncthreads();
#pragma unroll
  for (int i = 0; i < 2; ++i) {
    int c = i * 256 + tid, rn = c >> 3, ck = (c & 7) * 8;
    bf16x8 v;
#pragma unroll
    for (int j = 0; j < 8; ++j) v[j] = t[ck + j][rn];
    *(bf16x8*)(Wt + (size_t)(n0 + rn) * K + k0 + ck) = v;
  }
}

// ------------- v slice of qkv -> Vt[h][d][l] (tiled transpose) -------------
__global__ __launch_bounds__(256) void v_trans(const bf16_t* __restrict__ qkv,
                                               bf16_t* __restrict__ Vt) {
  __shared__ bf16_t t[64][136];
  const int l0 = blockIdx.x * 64, h = blockIdx.y, tid = threadIdx.x;
#pragma unroll
  for (int i = 0; i < 4; ++i) {
    int c = i * 256 + tid, row = c >> 4, cb = c & 15;
    *(bf16x8*)&t[row][cb * 8] =
        *(const bf16x8*)(qkv + (size_t)(l0 + row) * (3 * DIMC) + 2 * DIMC + h * HD + cb * 8);
  }
  __syncthreads();
#pragma unroll
  for (int i = 0; i < 4; ++i) {
    int c = i * 256 + tid, d = c >> 3, lb = c & 7;
    bf16x8 v;
#pragma unroll
    for (int j = 0; j < 8; ++j) v[j] = t[lb * 8 + j][d];
    *(bf16x8*)(Vt + ((size_t)h * HD + d) * L_C + l0 + lb * 8) = v;
  }
}

// ================= 256x256 4-phase GEMM: C = A(MxK) * Bt(NxK)^T + bias =================
// (unchanged from round 3: race-free invariant, xor-swizzled LDS, 45% MfmaUtil)
template <int OUT_BF16, int K>
__global__ __launch_bounds__(512, 1) void gemm8(const bf16_t* __restrict__ A,
                                                const bf16_t* __restrict__ Bt,
                                                const float* __restrict__ bias,
                                                bf16_t* __restrict__ Cb,
                                                float* __restrict__ Cf,
                                                int M, int N) {
  __shared__ __align__(16) char smem[131072];
  const int tid = threadIdx.x;
  const int wid = tid >> 6, lane = tid & 63;
  const int g = lane >> 4, r = lane & 15;
  const int wm = wid >> 2, wn = wid & 3;
  const int nb = gridDim.x * gridDim.y;
  const int bid = blockIdx.y * gridDim.x + blockIdx.x;
  const int swz = (bid & 7) * (nb >> 3) + (bid >> 3);
  const int bm = swz % gridDim.x, bn = swz / gridDim.x;
  const int row0 = bm * 256, col0 = bn * 256;

  auto stageA = [&](int buf, int half, int kt) {
#pragma unroll
    for (int i = 0; i < 2; ++i) {
      const int idx = i * 512 + tid;
      const int rl = idx >> 3, c = idx & 7;
      gload16(A + (size_t)(row0 + half * 128 + rl) * K + kt * 64 + ((c ^ (rl & 7)) << 3),
              smem + buf * 65536 + half * 16384 + (i * 512 + wid * 64) * 16);
    }
  };
  auto stageB = [&](int buf, int half, int kt) {
#pragma unroll
    for (int i = 0; i < 2; ++i) {
      const int idx = i * 512 + tid;
      const int rl = idx >> 3, c = idx & 7;
      gload16(Bt + (size_t)(col0 + half * 128 + rl) * K + kt * 64 + ((c ^ (rl & 7)) << 3),
              smem + buf * 65536 + 32768 + half * 16384 + (i * 512 + wid * 64) * 16);
    }
  };
  auto ldA = [&](int buf, int mi, int kk) {
    const int rh = mi * 16 + r;
    return *(const bf16x8*)(smem + buf * 65536 + wm * 16384 + rh * 128 +
                            (((kk * 4 + g) ^ (r & 7)) << 4));
  };
  auto ldB = [&](int buf, int ni, int kk) {
    const int rh = (wn & 1) * 64 + ni * 16 + r;
    return *(const bf16x8*)(smem + buf * 65536 + 32768 + (wn >> 1) * 16384 + rh * 128 +
                            (((kk * 4 + g) ^ (r & 7)) << 4));
  };

  f32x4 acc[8][4] = {};
  bf16x8 af[4][2], bfr[2][2];
  constexpr int nk = K / 64;

  stageA(0, 0, 0); stageA(0, 1, 0); stageB(0, 0, 0); stageB(0, 1, 0);
  VMCNT0();
  BARRIER();

  auto ktile = [&](int k, int cur) {
    const bool pf = (k + 1 < nk);
    // ---- phase 1
#pragma unroll
    for (int i = 0; i < 4; ++i)
#pragma unroll
      for (int kk = 0; kk < 2; ++kk) af[i][kk] = ldA(cur, i, kk);
#pragma unroll
    for (int j = 0; j < 2; ++j)
#pragma unroll
      for (int kk = 0; kk < 2; ++kk) bfr[j][kk] = ldB(cur, j, kk);
    if (pf) { stageA(cur ^ 1, 0, k + 1); stageA(cur ^ 1, 1, k + 1); }
    BARRIER();
    __builtin_amdgcn_s_setprio(1);
#pragma unroll
    for (int i = 0; i < 4; ++i)
#pragma unroll
      for (int j = 0; j < 2; ++j)
#pragma unroll
        for (int kk = 0; kk < 2; ++kk)
          acc[i][j] = MFMA16(af[i][kk], bfr[j][kk], acc[i][j]);
    __builtin_amdgcn_s_setprio(0);
    BARRIER();
    // ---- phase 2
#pragma unroll
    for (int i = 0; i < 4; ++i)
#pragma unroll
      for (int kk = 0; kk < 2; ++kk) af[i][kk] = ldA(cur, 4 + i, kk);
    if (pf) { stageB(cur ^ 1, 0, k + 1); stageB(cur ^ 1, 1, k + 1); }
    BARRIER();
    __builtin_amdgcn_s_setprio(1);
#pragma unroll
    for (int i = 0; i < 4; ++i)
#pragma unroll
      for (int j = 0; j < 2; ++j)
#pragma unroll
        for (int kk = 0; kk < 2; ++kk)
          acc[4 + i][j] = MFMA16(af[i][kk], bfr[j][kk], acc[4 + i][j]);
    __builtin_amdgcn_s_setprio(0);
    BARRIER();
    // ---- phase 3
#pragma unroll
    for (int j = 0; j < 2; ++j)
#pragma unroll
      for (int kk = 0; kk < 2; ++kk) bfr[j][kk] = ldB(cur, 2 + j, kk);
    BARRIER();
    __builtin_amdgcn_s_setprio(1);
#pragma unroll
    for (int i = 0; i < 4; ++i)
#pragma unroll
      for (int j = 0; j < 2; ++j)
#pragma unroll
        for (int kk = 0; kk < 2; ++kk)
          acc[4 + i][2 + j] = MFMA16(af[i][kk], bfr[j][kk], acc[4 + i][2 + j]);
    __builtin_amdgcn_s_setprio(0);
    BARRIER();
    // ---- phase 4
#pragma unroll
    for (int i = 0; i < 4; ++i)
#pragma unroll
      for (int kk = 0; kk < 2; ++kk) af[i][kk] = ldA(cur, i, kk);
    BARRIER();
    __builtin_amdgcn_s_setprio(1);
#pragma unroll
    for (int i = 0; i < 4; ++i)
#pragma unroll
      for (int j = 0; j < 2; ++j)
#pragma unroll
        for (int kk = 0; kk < 2; ++kk)
          acc[i][2 + j] = MFMA16(af[i][kk], bfr[j][kk], acc[i][2 + j]);
    __builtin_amdgcn_s_setprio(0);
    VMCNT0();
    BARRIER();
  };

  for (int kp = 0; kp < nk; kp += 2) { ktile(kp, 0); ktile(kp + 1, 1); }

#pragma unroll
  for (int mi = 0; mi < 8; ++mi)
#pragma unroll
    for (int ni = 0; ni < 4; ++ni)
#pragma unroll
      for (int p = 0; p < 4; ++p) {
        const int rr = row0 + wm * 128 + mi * 16 + 4 * g + p;
        const int cc = col0 + wn * 64 + ni * 16 + r;
        const float v = acc[mi][ni][p] + bias[cc];
        if (OUT_BF16) Cb[(size_t)rr * N + cc] = (bf16_t)v;
        else          Cf[(size_t)rr * N + cc] = v;
      }
}

// ---------------- RMSNorm(q,k) + RoPE -> Q[h][l][d], K[h][l][d] ----------------
__global__ __launch_bounds__(256) void norm_rope(const bf16_t* __restrict__ qkv,
                                                 const float* __restrict__ wq,
                                                 const float* __restrict__ wk,
                                                 const float* __restrict__ fcos,
                                                 const float* __restrict__ fsin,
                                                 bf16_t* __restrict__ Qo,
                                                 bf16_t* __restrict__ Ko) {
  const int l = blockIdx.x, tid = threadIdx.x;
  const bf16_t* row = qkv + (size_t)l * (3 * DIMC);
  float sq = 0.f, sk = 0.f;
  for (int i = tid; i < DIMC / 8; i += 256) {
    bf16x8 a = *(const bf16x8*)(row + i * 8);
    bf16x8 b = *(const bf16x8*)(row + DIMC + i * 8);
#pragma unroll
    for (int j = 0; j < 8; ++j) {
      float x = (float)a[j]; sq += x * x;
      float y = (float)b[j]; sk += y * y;
    }
  }
#pragma unroll
  for (int off = 32; off; off >>= 1) {
    sq += __shfl_xor(sq, off, 64);
    sk += __shfl_xor(sk, off, 64);
  }
  __shared__ float red[2][4];
  const int wid = tid >> 6, lane = tid & 63;
  if (!lane) { red[0][wid] = sq; red[1][wid] = sk; }
  __syncthreads();
  sq = red[0][0] + red[0][1] + red[0][2] + red[0][3];
  sk = red[1][0] + red[1][1] + red[1][2] + red[1][3];
  const float rq = rsqrtf(sq * (1.f / DIMC) + 1e-6f);
  const float rk = rsqrtf(sk * (1.f / DIMC) + 1e-6f);
  for (int i = tid; i < DIMC / 8; i += 256) {
    const int j0 = i * 8, h = j0 >> 7, d0 = j0 & 127;
    bf16x8 a = *(const bf16x8*)(row + j0);
    bf16x8 b = *(const bf16x8*)(row + DIMC + j0);
    f32x4 cA = *(const f32x4*)(fcos + (size_t)l * HD + d0);
    f32x4 cB = *(const f32x4*)(fcos + (size_t)l * HD + d0 + 4);
    f32x4 sA = *(const f32x4*)(fsin + (size_t)l * HD + d0);
    f32x4 sB = *(const f32x4*)(fsin + (size_t)l * HD + d0 + 4);
    f32x4 wqA = *(const f32x4*)(wq + j0), wqB = *(const f32x4*)(wq + j0 + 4);
    f32x4 wkA = *(const f32x4*)(wk + j0), wkB = *(const f32x4*)(wk + j0 + 4);
    float cc[8], ss[8], qn[8], kn[8];
#pragma unroll
    for (int j = 0; j < 4; ++j) {
      cc[j] = cA[j]; cc[4 + j] = cB[j];
      ss[j] = sA[j]; ss[4 + j] = sB[j];
      qn[j] = (float)a[j] * rq * wqA[j];
      qn[4 + j] = (float)a[4 + j] * rq * wqB[j];
      kn[j] = (float)b[j] * rk * wkA[j];
      kn[4 + j] = (float)b[4 + j] * rk * wkB[j];
    }
    bf16x8 oq, ok;
#pragma unroll
    for (int p = 0; p < 4; ++p) {
      const float c = cc[2 * p], s = ss[2 * p + 1];
      oq[2 * p]     = (bf16_t)(qn[2 * p] * c - qn[2 * p + 1] * s);
      oq[2 * p + 1] = (bf16_t)(qn[2 * p] * s + qn[2 * p + 1] * c);
      ok[2 * p]     = (bf16_t)(kn[2 * p] * c - kn[2 * p + 1] * s);
      ok[2 * p + 1] = (bf16_t)(kn[2 * p] * s + kn[2 * p + 1] * c);
    }
    *(bf16x8*)(Qo + ((size_t)h * L_C + l) * HD + d0) = oq;
    *(bf16x8*)(Ko + ((size_t)h * L_C + l) * HD + d0) = ok;
  }
}

// ---------------- flash attention: per (head, 128 q rows), T14 reg-staged prefetch ----------------
// 4 waves x 32 q-rows (2 rowgroups of 16). KVBLK=64. K/V tile t+1 global->regs while
// tile t computes; regs->LDS after the WAR barrier (plain __syncthreads structure).
__global__ __launch_bounds__(256, 2) void attn(const bf16_t* __restrict__ Q,
                                               const bf16_t* __restrict__ Kg,
                                               const bf16_t* __restrict__ Vt,
                                               bf16_t* __restrict__ O) {
  __shared__ bf16_t k_lds[64 * HD];   // [key][d], XOR-swizzled
  __shared__ bf16_t v_lds[HD * 64];   // [d][key], XOR-swizzled
  __shared__ bf16_t p_lds[4][2][16 * 72];
  const int tid = threadIdx.x, wid = tid >> 6, lane = tid & 63;
  const int g = lane >> 4, r = lane & 15;
  const int h = blockIdx.y;
  const int q0 = blockIdx.x * 128 + wid * 32;
  bf16x8 qf[2][4];
#pragma unroll
  for (int rg = 0; rg < 2; ++rg) {
    const bf16_t* qrow = Q + ((size_t)h * L_C + q0 + rg * 16 + r) * HD;
#pragma unroll
    for (int ks = 0; ks < 4; ++ks) qf[rg][ks] = *(const bf16x8*)(qrow + ks * 32 + g * 8);
  }
  f32x4 oacc[2][8] = {};
  float m_i[2][4], l_i[2][4];
#pragma unroll
  for (int rg = 0; rg < 2; ++rg)
#pragma unroll
    for (int p = 0; p < 4; ++p) { m_i[rg][p] = -1e30f; l_i[rg][p] = 0.f; }
  const float scale = 0.08838834764831845f;  // 1/sqrt(128)

  bf16x8 kreg[4], vreg[4];
  auto load_kv = [&](int kv0) {
#pragma unroll
    for (int i = 0; i < 4; ++i) {
      const int c = i * 256 + tid;
      const int krow = c >> 4, kcb = c & 15;
      kreg[i] = *(const bf16x8*)(Kg + ((size_t)h * L_C + kv0 + krow) * HD + kcb * 8);
      const int vrow = c >> 3, vcb = c & 7;
      vreg[i] = *(const bf16x8*)(Vt + ((size_t)h * HD + vrow) * L_C + kv0 + vcb * 8);
    }
  };
  load_kv(0);

  for (int kv0 = 0; kv0 < L_C; kv0 += 64) {
    __syncthreads();  // WAR: all waves done reading previous LDS tile
#pragma unroll
    for (int i = 0; i < 4; ++i) {
      const int c = i * 256 + tid;
      const int krow = c >> 4, kcb = c & 15;
      *(bf16x8*)((char*)k_lds + krow * 256 + ((kcb * 16) ^ ((krow & 7) << 4))) = kreg[i];
      const int vrow = c >> 3, vcb = c & 7;
      *(bf16x8*)((char*)v_lds + vrow * 128 + ((vcb * 16) ^ ((vrow & 7) << 4))) = vreg[i];
    }
    if (kv0 + 64 < L_C) load_kv(kv0 + 64);  // in flight under this tile's compute
    __syncthreads();  // RAW: LDS tile ready

#pragma unroll
    for (int rg = 0; rg < 2; ++rg) {
      // QK^T
      float pv[4][4];
#pragma unroll
      for (int nf = 0; nf < 4; ++nf) {
        f32x4 sacc = {0.f, 0.f, 0.f, 0.f};
        const int key = nf * 16 + r;
#pragma unroll
        for (int ks = 0; ks < 4; ++ks) {
          bf16x8 kf = *(const bf16x8*)((const char*)k_lds + key * 256 +
                                       ((ks * 64 + g * 16) ^ ((key & 7) << 4)));
          sacc = MFMA16(qf[rg][ks], kf, sacc);
        }
#pragma unroll
        for (int p = 0; p < 4; ++p) pv[nf][p] = sacc[p] * scale;
      }
      // online softmax (row lives across the 16 lanes of the lane&15 group)
      float mnew[4];
#pragma unroll
      for (int p = 0; p < 4; ++p)
        mnew[p] = fmaxf(fmaxf(pv[0][p], pv[1][p]), fmaxf(pv[2][p], pv[3][p]));
#pragma unroll
      for (int m = 1; m < 16; m <<= 1)
#pragma unroll
        for (int p = 0; p < 4; ++p) mnew[p] = fmaxf(mnew[p], __shfl_xor(mnew[p], m, 64));
      float alpha[4], rsum[4];
#pragma unroll
      for (int p = 0; p < 4; ++p) {
        const float mi = fmaxf(m_i[rg][p], mnew[p]);
        alpha[p] = __expf(m_i[rg][p] - mi);
        m_i[rg][p] = mi;
        rsum[p] = 0.f;
      }
#pragma unroll
      for (int nf = 0; nf < 4; ++nf)
#pragma unroll
        for (int p = 0; p < 4; ++p) {
          pv[nf][p] = __expf(pv[nf][p] - m_i[rg][p]);
          rsum[p] += pv[nf][p];
        }
#pragma unroll
      for (int nf = 0; nf < 4; ++nf)
#pragma unroll
        for (int p = 0; p < 4; ++p)
          p_lds[wid][rg][(4 * g + p) * 72 + nf * 16 + r] = (bf16_t)pv[nf][p];
#pragma unroll
      for (int m = 1; m < 16; m <<= 1)
#pragma unroll
        for (int p = 0; p < 4; ++p) rsum[p] += __shfl_xor(rsum[p], m, 64);
#pragma unroll
      for (int p = 0; p < 4; ++p) l_i[rg][p] = l_i[rg][p] * alpha[p] + rsum[p];
#pragma unroll
      for (int nf = 0; nf < 8; ++nf)
#pragma unroll
        for (int p = 0; p < 4; ++p) oacc[rg][nf][p] *= alpha[p];
      // PV
      bf16x8 pf0 = *(const bf16x8*)&p_lds[wid][rg][r * 72 + 8 * g];
      bf16x8 pf1 = *(const bf16x8*)&p_lds[wid][rg][r * 72 + 32 + 8 * g];
#pragma unroll
      for (int nf = 0; nf < 8; ++nf) {
        const int d = nf * 16 + r;
        bf16x8 vf0 = *(const bf16x8*)((const char*)v_lds + d * 128 +
                                      ((g * 16) ^ ((d & 7) << 4)));
        oacc[rg][nf] = MFMA16(pf0, vf0, oacc[rg][nf]);
        bf16x8 vf1 = *(const bf16x8*)((const char*)v_lds + d * 128 +
                                      ((64 + g * 16) ^ ((d & 7) << 4)));
        oacc[rg][nf] = MFMA16(pf1, vf1, oacc[rg][nf]);
      }
    }
  }
#pragma unroll
  for (int rg = 0; rg < 2; ++rg)
#pragma unroll
    for (int p = 0; p < 4; ++p) {
      const float inv = 1.f / l_i[rg][p];
      const int rowg = q0 + rg * 16 + 4 * g + p;
#pragma unroll
      for (int nf = 0; nf < 8; ++nf) {
        const int d = nf * 16 + r;
        O[(size_t)rowg * DIMC + h * HD + d] = (bf16_t)(oacc[rg][nf][p] * inv);
      }
    }
}

// ---------------- launch ----------------
extern "C" void kernel_launch(void* const* d_in, const int* in_sizes, int n_in,
                              void* d_out, int out_size, void* d_ws, size_t ws_size,
                              hipStream_t stream) {
  const float* hidden = (const float*)d_in[0];
  const float* fcos   = (const float*)d_in[1];
  const float* fsin   = (const float*)d_in[2];
  const float* Wqkv   = (const float*)d_in[3];
  const float* bqkv   = (const float*)d_in[4];
  const float* wnq    = (const float*)d_in[5];
  const float* wnk    = (const float*)d_in[6];
  const float* Wout   = (const float*)d_in[7];
  const float* bout   = (const float*)d_in[8];
  float* out = (float*)d_out;

  char* ws = (char*)d_ws;
  size_t off = 0;
  auto alloc = [&](size_t bytes) {
    void* p = ws + off;
    off += (bytes + 255) & ~(size_t)255;
    return p;
  };
  bf16_t* X   = (bf16_t*)alloc((size_t)L_C * DIMC * 2);
  bf16_t* WQT = (bf16_t*)alloc((size_t)3 * DIMC * DIMC * 2);
  bf16_t* WOT = (bf16_t*)alloc((size_t)DIMC * DIMC * 2);
  bf16_t* QKV = (bf16_t*)alloc((size_t)L_C * 3 * DIMC * 2);
  bf16_t* Qb  = (bf16_t*)alloc((size_t)L_C * DIMC * 2);
  bf16_t* Kb  = (bf16_t*)alloc((size_t)L_C * DIMC * 2);
  bf16_t* VT  = (bf16_t*)alloc((size_t)L_C * DIMC * 2);
  bf16_t* Ob  = X;  // X dead after gemm1; reuse for attention output

  f32_to_bf16<<<2048, 256, 0, stream>>>(hidden, X, (size_t)L_C * DIMC / 8);
  wtrans<<<dim3(DIMC / 64, 3 * DIMC / 64), 256, 0, stream>>>(Wqkv, WQT, DIMC, 3 * DIMC);
  wtrans<<<dim3(DIMC / 64, DIMC / 64), 256, 0, stream>>>(Wout, WOT, DIMC, DIMC);
  gemm8<1, DIMC><<<dim3(L_C / 256, 3 * DIMC / 256), 512, 0, stream>>>(
      X, WQT, bqkv, QKV, nullptr, L_C, 3 * DIMC);
  norm_rope<<<L_C, 256, 0, stream>>>(QKV, wnq, wnk, fcos, fsin, Qb, Kb);
  v_trans<<<dim3(L_C / 64, NHEADS), 256, 0, stream>>>(QKV, VT);
  attn<<<dim3(L_C / 128, NHEADS), 256, 0, stream>>>(Qb, Kb, VT, Ob);
  gemm8<0, DIMC><<<dim3(L_C / 256, DIMC / 256), 512, 0, stream>>>(
      Ob, WOT, bout, nullptr, out, L_C, DIMC);
}

// Round 5
// 811.263 us; speedup vs baseline: 1.2640x; 1.0057x over previous
//
#include <hip/hip_runtime.h>
#include <cstdint>
#include <cstddef>

#define L_C   2048
#define DIMC  5120
#define HD    128
#define NHEADS 40

typedef __bf16 bf16_t;
typedef __bf16 bf16x8 __attribute__((ext_vector_type(8)));
typedef __bf16 bf16x4 __attribute__((ext_vector_type(4)));
typedef float  f32x4  __attribute__((ext_vector_type(4)));

#define MFMA16(A,B,C) __builtin_amdgcn_mfma_f32_16x16x32_bf16((A),(B),(C),0,0,0)
#define BARRIER() __builtin_amdgcn_s_barrier()
#define VMCNT0() asm volatile("s_waitcnt vmcnt(0)" ::: "memory")

__device__ __forceinline__ void gload16(const void* g, void* l) {
  __builtin_amdgcn_global_load_lds(
      (__attribute__((address_space(1))) void*)(void*)g,
      (__attribute__((address_space(3))) void*)l, 16, 0, 0);
}

// ---------------- f32 -> bf16 elementwise ----------------
__global__ __launch_bounds__(256) void f32_to_bf16(const float* __restrict__ in,
                                                   bf16_t* __restrict__ out, size_t n8) {
  size_t i = (size_t)blockIdx.x * blockDim.x + threadIdx.x;
  size_t stride = (size_t)gridDim.x * blockDim.x;
  for (; i < n8; i += stride) {
    f32x4 a = *(const f32x4*)(in + i * 8);
    f32x4 b = *(const f32x4*)(in + i * 8 + 4);
    bf16x8 o;
#pragma unroll
    for (int j = 0; j < 4; ++j) { o[j] = (bf16_t)a[j]; o[4 + j] = (bf16_t)b[j]; }
    *(bf16x8*)(out + i * 8) = o;
  }
}

// ------------- W [K][N] f32 -> Wt [N][K] bf16 (tiled transpose) -------------
__global__ __launch_bounds__(256) void wtrans(const float* __restrict__ W,
                                              bf16_t* __restrict__ Wt, int K, int N) {
  __shared__ bf16_t t[64][68];
  const int k0 = blockIdx.x * 64, n0 = blockIdx.y * 64, tid = threadIdx.x;
#pragma unroll
  for (int i = 0; i < 4; ++i) {
    int c = i * 256 + tid, rk = c >> 4, cn = (c & 15) * 4;
    f32x4 v = *(const f32x4*)(W + (size_t)(k0 + rk) * N + n0 + cn);
    bf16x4 o;
#pragma unroll
    for (int j = 0; j < 4; ++j) o[j] = (bf16_t)v[j];
    *(bf16x4*)&t[rk][cn] = o;
  }
  __syncthreads();
#pragma unroll
  for (int i = 0; i < 2; ++i) {
    int c = i * 256 + tid, rn = c >> 3, ck = (c & 7) * 8;
    bf16x8 v;
#pragma unroll
    for (int j = 0; j < 8; ++j) v[j] = t[ck + j][rn];
    *(bf16x8*)(Wt + (size_t)(n0 + rn) * K + k0 + ck) = v;
  }
}

// ------------- v slice of qkv -> Vt[h][d][l] (tiled transpose) -------------
__global__ __launch_bounds__(256) void v_trans(const bf16_t* __restrict__ qkv,
                                               bf16_t* __restrict__ Vt) {
  __shared__ bf16_t t[64][136];
  const int l0 = blockIdx.x * 64, h = blockIdx.y, tid = threadIdx.x;
#pragma unroll
  for (int i = 0; i < 4; ++i) {
    int c = i * 256 + tid, row = c >> 4, cb = c & 15;
    *(bf16x8*)&t[row][cb * 8] =
        *(const bf16x8*)(qkv + (size_t)(l0 + row) * (3 * DIMC) + 2 * DIMC + h * HD + cb * 8);
  }
  __syncthreads();
#pragma unroll
  for (int i = 0; i < 4; ++i) {
    int c = i * 256 + tid, d = c >> 3, lb = c & 7;
    bf16x8 v;
#pragma unroll
    for (int j = 0; j < 8; ++j) v[j] = t[lb * 8 + j][d];
    *(bf16x8*)(Vt + ((size_t)h * HD + d) * L_C + l0 + lb * 8) = v;
  }
}

// ================= 256x256 4-phase GEMM: C = A(MxK) * Bt(NxK)^T + bias =================
// Race-free invariant (round 3) + zero re-read schedule: all 4 B fragment sets held in
// registers for the tile; quadrant order Q00->Q01->Q11->Q10 so each operand byte is
// ds_read exactly once (24 b128/tile/thread vs 32).
template <int OUT_BF16, int K>
__global__ __launch_bounds__(512, 1) void gemm8(const bf16_t* __restrict__ A,
                                                const bf16_t* __restrict__ Bt,
                                                const float* __restrict__ bias,
                                                bf16_t* __restrict__ Cb,
                                                float* __restrict__ Cf,
                                                int M, int N) {
  __shared__ __align__(16) char smem[131072];
  const int tid = threadIdx.x;
  const int wid = tid >> 6, lane = tid & 63;
  const int g = lane >> 4, r = lane & 15;
  const int wm = wid >> 2, wn = wid & 3;
  const int nb = gridDim.x * gridDim.y;
  const int bid = blockIdx.y * gridDim.x + blockIdx.x;
  const int swz = (bid & 7) * (nb >> 3) + (bid >> 3);
  const int bm = swz % gridDim.x, bn = swz / gridDim.x;
  const int row0 = bm * 256, col0 = bn * 256;

  auto stageA = [&](int buf, int half, int kt) {
#pragma unroll
    for (int i = 0; i < 2; ++i) {
      const int idx = i * 512 + tid;
      const int rl = idx >> 3, c = idx & 7;
      gload16(A + (size_t)(row0 + half * 128 + rl) * K + kt * 64 + ((c ^ (rl & 7)) << 3),
              smem + buf * 65536 + half * 16384 + (i * 512 + wid * 64) * 16);
    }
  };
  auto stageB = [&](int buf, int half, int kt) {
#pragma unroll
    for (int i = 0; i < 2; ++i) {
      const int idx = i * 512 + tid;
      const int rl = idx >> 3, c = idx & 7;
      gload16(Bt + (size_t)(col0 + half * 128 + rl) * K + kt * 64 + ((c ^ (rl & 7)) << 3),
              smem + buf * 65536 + 32768 + half * 16384 + (i * 512 + wid * 64) * 16);
    }
  };
  auto ldA = [&](int buf, int mi, int kk) {
    const int rh = mi * 16 + r;
    return *(const bf16x8*)(smem + buf * 65536 + wm * 16384 + rh * 128 +
                            (((kk * 4 + g) ^ (r & 7)) << 4));
  };
  auto ldB = [&](int buf, int ni, int kk) {
    const int rh = (wn & 1) * 64 + ni * 16 + r;
    return *(const bf16x8*)(smem + buf * 65536 + 32768 + (wn >> 1) * 16384 + rh * 128 +
                            (((kk * 4 + g) ^ (r & 7)) << 4));
  };

  f32x4 acc[8][4] = {};
  bf16x8 af[4][2], bfr[4][2];
  constexpr int nk = K / 64;

  stageA(0, 0, 0); stageA(0, 1, 0); stageB(0, 0, 0); stageB(0, 1, 0);
  VMCNT0();
  BARRIER();

  auto ktile = [&](int k, int cur) {
    const bool pf = (k + 1 < nk);
    // ---- phase 1: read af(mi0-3) + bfr(ni0-1); stage A(k+1); compute Q00
#pragma unroll
    for (int i = 0; i < 4; ++i)
#pragma unroll
      for (int kk = 0; kk < 2; ++kk) af[i][kk] = ldA(cur, i, kk);
#pragma unroll
    for (int j = 0; j < 2; ++j)
#pragma unroll
      for (int kk = 0; kk < 2; ++kk) bfr[j][kk] = ldB(cur, j, kk);
    if (pf) { stageA(cur ^ 1, 0, k + 1); stageA(cur ^ 1, 1, k + 1); }
    BARRIER();
    __builtin_amdgcn_s_setprio(1);
#pragma unroll
    for (int i = 0; i < 4; ++i)
#pragma unroll
      for (int j = 0; j < 2; ++j)
#pragma unroll
        for (int kk = 0; kk < 2; ++kk)
          acc[i][j] = MFMA16(af[i][kk], bfr[j][kk], acc[i][j]);
    __builtin_amdgcn_s_setprio(0);
    BARRIER();
    // ---- phase 2: read bfr(ni2-3); stage B(k+1); compute Q01 (af mi0-3 live)
#pragma unroll
    for (int j = 0; j < 2; ++j)
#pragma unroll
      for (int kk = 0; kk < 2; ++kk) bfr[2 + j][kk] = ldB(cur, 2 + j, kk);
    if (pf) { stageB(cur ^ 1, 0, k + 1); stageB(cur ^ 1, 1, k + 1); }
    BARRIER();
    __builtin_amdgcn_s_setprio(1);
#pragma unroll
    for (int i = 0; i < 4; ++i)
#pragma unroll
      for (int j = 0; j < 2; ++j)
#pragma unroll
        for (int kk = 0; kk < 2; ++kk)
          acc[i][2 + j] = MFMA16(af[i][kk], bfr[2 + j][kk], acc[i][2 + j]);
    __builtin_amdgcn_s_setprio(0);
    BARRIER();
    // ---- phase 3: read af(mi4-7); compute Q11 (bfr ni2-3 live)
#pragma unroll
    for (int i = 0; i < 4; ++i)
#pragma unroll
      for (int kk = 0; kk < 2; ++kk) af[i][kk] = ldA(cur, 4 + i, kk);
    BARRIER();
    __builtin_amdgcn_s_setprio(1);
#pragma unroll
    for (int i = 0; i < 4; ++i)
#pragma unroll
      for (int j = 0; j < 2; ++j)
#pragma unroll
        for (int kk = 0; kk < 2; ++kk)
          acc[4 + i][2 + j] = MFMA16(af[i][kk], bfr[2 + j][kk], acc[4 + i][2 + j]);
    __builtin_amdgcn_s_setprio(0);
    BARRIER();
    // ---- phase 4: no reads; compute Q10 (af mi4-7, bfr ni0-1 live); drain
    __builtin_amdgcn_s_setprio(1);
#pragma unroll
    for (int i = 0; i < 4; ++i)
#pragma unroll
      for (int j = 0; j < 2; ++j)
#pragma unroll
        for (int kk = 0; kk < 2; ++kk)
          acc[4 + i][j] = MFMA16(af[i][kk], bfr[j][kk], acc[4 + i][j]);
    __builtin_amdgcn_s_setprio(0);
    VMCNT0();   // tile k+1's stages (issued phases 1-2) landed
    BARRIER();
  };

  for (int kp = 0; kp < nk; kp += 2) { ktile(kp, 0); ktile(kp + 1, 1); }

#pragma unroll
  for (int mi = 0; mi < 8; ++mi)
#pragma unroll
    for (int ni = 0; ni < 4; ++ni)
#pragma unroll
      for (int p = 0; p < 4; ++p) {
        const int rr = row0 + wm * 128 + mi * 16 + 4 * g + p;
        const int cc = col0 + wn * 64 + ni * 16 + r;
        const float v = acc[mi][ni][p] + bias[cc];
        if (OUT_BF16) Cb[(size_t)rr * N + cc] = (bf16_t)v;
        else          Cf[(size_t)rr * N + cc] = v;
      }
}

// ---------------- RMSNorm(q,k) + RoPE -> Q[h][l][d], K[h][l][d] ----------------
__global__ __launch_bounds__(256) void norm_rope(const bf16_t* __restrict__ qkv,
                                                 const float* __restrict__ wq,
                                                 const float* __restrict__ wk,
                                                 const float* __restrict__ fcos,
                                                 const float* __restrict__ fsin,
                                                 bf16_t* __restrict__ Qo,
                                                 bf16_t* __restrict__ Ko) {
  const int l = blockIdx.x, tid = threadIdx.x;
  const bf16_t* row = qkv + (size_t)l * (3 * DIMC);
  float sq = 0.f, sk = 0.f;
  for (int i = tid; i < DIMC / 8; i += 256) {
    bf16x8 a = *(const bf16x8*)(row + i * 8);
    bf16x8 b = *(const bf16x8*)(row + DIMC + i * 8);
#pragma unroll
    for (int j = 0; j < 8; ++j) {
      float x = (float)a[j]; sq += x * x;
      float y = (float)b[j]; sk += y * y;
    }
  }
#pragma unroll
  for (int off = 32; off; off >>= 1) {
    sq += __shfl_xor(sq, off, 64);
    sk += __shfl_xor(sk, off, 64);
  }
  __shared__ float red[2][4];
  const int wid = tid >> 6, lane = tid & 63;
  if (!lane) { red[0][wid] = sq; red[1][wid] = sk; }
  __syncthreads();
  sq = red[0][0] + red[0][1] + red[0][2] + red[0][3];
  sk = red[1][0] + red[1][1] + red[1][2] + red[1][3];
  const float rq = rsqrtf(sq * (1.f / DIMC) + 1e-6f);
  const float rk = rsqrtf(sk * (1.f / DIMC) + 1e-6f);
  for (int i = tid; i < DIMC / 8; i += 256) {
    const int j0 = i * 8, h = j0 >> 7, d0 = j0 & 127;
    bf16x8 a = *(const bf16x8*)(row + j0);
    bf16x8 b = *(const bf16x8*)(row + DIMC + j0);
    f32x4 cA = *(const f32x4*)(fcos + (size_t)l * HD + d0);
    f32x4 cB = *(const f32x4*)(fcos + (size_t)l * HD + d0 + 4);
    f32x4 sA = *(const f32x4*)(fsin + (size_t)l * HD + d0);
    f32x4 sB = *(const f32x4*)(fsin + (size_t)l * HD + d0 + 4);
    f32x4 wqA = *(const f32x4*)(wq + j0), wqB = *(const f32x4*)(wq + j0 + 4);
    f32x4 wkA = *(const f32x4*)(wk + j0), wkB = *(const f32x4*)(wk + j0 + 4);
    float cc[8], ss[8], qn[8], kn[8];
#pragma unroll
    for (int j = 0; j < 4; ++j) {
      cc[j] = cA[j]; cc[4 + j] = cB[j];
      ss[j] = sA[j]; ss[4 + j] = sB[j];
      qn[j] = (float)a[j] * rq * wqA[j];
      qn[4 + j] = (float)a[4 + j] * rq * wqB[j];
      kn[j] = (float)b[j] * rk * wkA[j];
      kn[4 + j] = (float)b[4 + j] * rk * wkB[j];
    }
    bf16x8 oq, ok;
#pragma unroll
    for (int p = 0; p < 4; ++p) {
      const float c = cc[2 * p], s = ss[2 * p + 1];
      oq[2 * p]     = (bf16_t)(qn[2 * p] * c - qn[2 * p + 1] * s);
      oq[2 * p + 1] = (bf16_t)(qn[2 * p] * s + qn[2 * p + 1] * c);
      ok[2 * p]     = (bf16_t)(kn[2 * p] * c - kn[2 * p + 1] * s);
      ok[2 * p + 1] = (bf16_t)(kn[2 * p] * s + kn[2 * p + 1] * c);
    }
    *(bf16x8*)(Qo + ((size_t)h * L_C + l) * HD + d0) = oq;
    *(bf16x8*)(Ko + ((size_t)h * L_C + l) * HD + d0) = ok;
  }
}

// ---------------- flash attention: per (head, 128 q rows) ----------------
// 4 waves x 32 q-rows (2 rowgroups). K/V fragments hoisted: read once, feed both
// rowgroups (36 vs 68 ds_read_b128/wave/tile). Head->XCD swizzle: all 16 q-blocks
// of a head land on one XCD (KV L2-resident).
__global__ __launch_bounds__(256, 2) void attn(const bf16_t* __restrict__ Q,
                                               const bf16_t* __restrict__ Kg,
                                               const bf16_t* __restrict__ Vt,
                                               bf16_t* __restrict__ O) {
  __shared__ bf16_t k_lds[64 * HD];   // [key][d], XOR-swizzled
  __shared__ bf16_t v_lds[HD * 64];   // [d][key], XOR-swizzled
  __shared__ bf16_t p_lds[4][2][16 * 72];
  const int tid = threadIdx.x, wid = tid >> 6, lane = tid & 63;
  const int g = lane >> 4, r = lane & 15;
  // head->XCD swizzle: bid = grp + 8*(hsub*16 + x), h = hsub*8 + grp  (bijective)
  const int bid = blockIdx.x;
  const int grp = bid & 7, inner = bid >> 3;
  const int h = (inner >> 4) * 8 + grp;
  const int q0 = (inner & 15) * 128 + wid * 32;
  bf16x8 qf[2][4];
#pragma unroll
  for (int rg = 0; rg < 2; ++rg) {
    const bf16_t* qrow = Q + ((size_t)h * L_C + q0 + rg * 16 + r) * HD;
#pragma unroll
    for (int ks = 0; ks < 4; ++ks) qf[rg][ks] = *(const bf16x8*)(qrow + ks * 32 + g * 8);
  }
  f32x4 oacc[2][8] = {};
  float m_i[2][4], l_i[2][4];
#pragma unroll
  for (int rg = 0; rg < 2; ++rg)
#pragma unroll
    for (int p = 0; p < 4; ++p) { m_i[rg][p] = -1e30f; l_i[rg][p] = 0.f; }
  const float scale = 0.08838834764831845f;  // 1/sqrt(128)

  bf16x8 kreg[4], vreg[4];
  auto load_kv = [&](int kv0) {
#pragma unroll
    for (int i = 0; i < 4; ++i) {
      const int c = i * 256 + tid;
      const int krow = c >> 4, kcb = c & 15;
      kreg[i] = *(const bf16x8*)(Kg + ((size_t)h * L_C + kv0 + krow) * HD + kcb * 8);
      const int vrow = c >> 3, vcb = c & 7;
      vreg[i] = *(const bf16x8*)(Vt + ((size_t)h * HD + vrow) * L_C + kv0 + vcb * 8);
    }
  };
  load_kv(0);

  for (int kv0 = 0; kv0 < L_C; kv0 += 64) {
    __syncthreads();  // WAR: all waves done reading previous LDS tile
#pragma unroll
    for (int i = 0; i < 4; ++i) {
      const int c = i * 256 + tid;
      const int krow = c >> 4, kcb = c & 15;
      *(bf16x8*)((char*)k_lds + krow * 256 + ((kcb * 16) ^ ((krow & 7) << 4))) = kreg[i];
      const int vrow = c >> 3, vcb = c & 7;
      *(bf16x8*)((char*)v_lds + vrow * 128 + ((vcb * 16) ^ ((vrow & 7) << 4))) = vreg[i];
    }
    if (kv0 + 64 < L_C) load_kv(kv0 + 64);  // in flight under this tile's compute
    __syncthreads();  // RAW: LDS tile ready

    // QK^T — kf read once, feeds both rowgroups
    float pv[2][4][4];
#pragma unroll
    for (int nf = 0; nf < 4; ++nf) {
      f32x4 s0 = {0.f, 0.f, 0.f, 0.f}, s1 = {0.f, 0.f, 0.f, 0.f};
      const int key = nf * 16 + r;
#pragma unroll
      for (int ks = 0; ks < 4; ++ks) {
        bf16x8 kf = *(const bf16x8*)((const char*)k_lds + key * 256 +
                                     ((ks * 64 + g * 16) ^ ((key & 7) << 4)));
        s0 = MFMA16(qf[0][ks], kf, s0);
        s1 = MFMA16(qf[1][ks], kf, s1);
      }
#pragma unroll
      for (int p = 0; p < 4; ++p) { pv[0][nf][p] = s0[p] * scale; pv[1][nf][p] = s1[p] * scale; }
    }
    // online softmax per rowgroup (row across the 16 lanes of the lane&15 group)
#pragma unroll
    for (int rg = 0; rg < 2; ++rg) {
      float mnew[4];
#pragma unroll
      for (int p = 0; p < 4; ++p)
        mnew[p] = fmaxf(fmaxf(pv[rg][0][p], pv[rg][1][p]), fmaxf(pv[rg][2][p], pv[rg][3][p]));
#pragma unroll
      for (int m = 1; m < 16; m <<= 1)
#pragma unroll
        for (int p = 0; p < 4; ++p) mnew[p] = fmaxf(mnew[p], __shfl_xor(mnew[p], m, 64));
      float alpha[4], rsum[4];
#pragma unroll
      for (int p = 0; p < 4; ++p) {
        const float mi = fmaxf(m_i[rg][p], mnew[p]);
        alpha[p] = __expf(m_i[rg][p] - mi);
        m_i[rg][p] = mi;
        rsum[p] = 0.f;
      }
#pragma unroll
      for (int nf = 0; nf < 4; ++nf)
#pragma unroll
        for (int p = 0; p < 4; ++p) {
          pv[rg][nf][p] = __expf(pv[rg][nf][p] - m_i[rg][p]);
          rsum[p] += pv[rg][nf][p];
        }
#pragma unroll
      for (int nf = 0; nf < 4; ++nf)
#pragma unroll
        for (int p = 0; p < 4; ++p)
          p_lds[wid][rg][(4 * g + p) * 72 + nf * 16 + r] = (bf16_t)pv[rg][nf][p];
#pragma unroll
      for (int m = 1; m < 16; m <<= 1)
#pragma unroll
        for (int p = 0; p < 4; ++p) rsum[p] += __shfl_xor(rsum[p], m, 64);
#pragma unroll
      for (int p = 0; p < 4; ++p) l_i[rg][p] = l_i[rg][p] * alpha[p] + rsum[p];
#pragma unroll
      for (int nf = 0; nf < 8; ++nf)
#pragma unroll
        for (int p = 0; p < 4; ++p) oacc[rg][nf][p] *= alpha[p];
    }
    // PV — vf read once, feeds both rowgroups
    bf16x8 pf0[2], pf1[2];
#pragma unroll
    for (int rg = 0; rg < 2; ++rg) {
      pf0[rg] = *(const bf16x8*)&p_lds[wid][rg][r * 72 + 8 * g];
      pf1[rg] = *(const bf16x8*)&p_lds[wid][rg][r * 72 + 32 + 8 * g];
    }
#pragma unroll
    for (int nf = 0; nf < 8; ++nf) {
      const int d = nf * 16 + r;
      bf16x8 vf0 = *(const bf16x8*)((const char*)v_lds + d * 128 +
                                    ((g * 16) ^ ((d & 7) << 4)));
      bf16x8 vf1 = *(const bf16x8*)((const char*)v_lds + d * 128 +
                                    ((64 + g * 16) ^ ((d & 7) << 4)));
#pragma unroll
      for (int rg = 0; rg < 2; ++rg) {
        oacc[rg][nf] = MFMA16(pf0[rg], vf0, oacc[rg][nf]);
        oacc[rg][nf] = MFMA16(pf1[rg], vf1, oacc[rg][nf]);
      }
    }
  }
#pragma unroll
  for (int rg = 0; rg < 2; ++rg)
#pragma unroll
    for (int p = 0; p < 4; ++p) {
      const float inv = 1.f / l_i[rg][p];
      const int rowg = q0 + rg * 16 + 4 * g + p;
#pragma unroll
      for (int nf = 0; nf < 8; ++nf) {
        const int d = nf * 16 + r;
        O[(size_t)rowg * DIMC + h * HD + d] = (bf16_t)(oacc[rg][nf][p] * inv);
      }
    }
}

// ---------------- launch ----------------
extern "C" void kernel_launch(void* const* d_in, const int* in_sizes, int n_in,
                              void* d_out, int out_size, void* d_ws, size_t ws_size,
                              hipStream_t stream) {
  const float* hidden = (const float*)d_in[0];
  const float* fcos   = (const float*)d_in[1];
  const float* fsin   = (const float*)d_in[2];
  const float* Wqkv   = (const float*)d_in[3];
  const float* bqkv   = (const float*)d_in[4];
  const float* wnq    = (const float*)d_in[5];
  const float* wnk    = (const float*)d_in[6];
  const float* Wout   = (const float*)d_in[7];
  const float* bout   = (const float*)d_in[8];
  float* out = (float*)d_out;

  char* ws = (char*)d_ws;
  size_t off = 0;
  auto alloc = [&](size_t bytes) {
    void* p = ws + off;
    off += (bytes + 255) & ~(size_t)255;
    return p;
  };
  bf16_t* X   = (bf16_t*)alloc((size_t)L_C * DIMC * 2);
  bf16_t* WQT = (bf16_t*)alloc((size_t)3 * DIMC * DIMC * 2);
  bf16_t* WOT = (bf16_t*)alloc((size_t)DIMC * DIMC * 2);
  bf16_t* QKV = (bf16_t*)alloc((size_t)L_C * 3 * DIMC * 2);
  bf16_t* Qb  = (bf16_t*)alloc((size_t)L_C * DIMC * 2);
  bf16_t* Kb  = (bf16_t*)alloc((size_t)L_C * DIMC * 2);
  bf16_t* VT  = (bf16_t*)alloc((size_t)L_C * DIMC * 2);
  bf16_t* Ob  = X;  // X dead after gemm1; reuse for attention output

  f32_to_bf16<<<2048, 256, 0, stream>>>(hidden, X, (size_t)L_C * DIMC / 8);
  wtrans<<<dim3(DIMC / 64, 3 * DIMC / 64), 256, 0, stream>>>(Wqkv, WQT, DIMC, 3 * DIMC);
  wtrans<<<dim3(DIMC / 64, DIMC / 64), 256, 0, stream>>>(Wout, WOT, DIMC, DIMC);
  gemm8<1, DIMC><<<dim3(L_C / 256, 3 * DIMC / 256), 512, 0, stream>>>(
      X, WQT, bqkv, QKV, nullptr, L_C, 3 * DIMC);
  norm_rope<<<L_C, 256, 0, stream>>>(QKV, wnq, wnk, fcos, fsin, Qb, Kb);
  v_trans<<<dim3(L_C / 64, NHEADS), 256, 0, stream>>>(QKV, VT);
  attn<<<(L_C / 128) * NHEADS, 256, 0, stream>>>(Qb, Kb, VT, Ob);
  gemm8<0, DIMC><<<dim3(L_C / 256, DIMC / 256), 512, 0, stream>>>(
      Ob, WOT, bout, nullptr, out, L_C, DIMC);
}

// Round 6
// 803.808 us; speedup vs baseline: 1.2757x; 1.0093x over previous
//
#include <hip/hip_runtime.h>
#include <cstdint>
#include <cstddef>

#define L_C   2048
#define DIMC  5120
#define HD    128
#define NHEADS 40

typedef __bf16 bf16_t;
typedef __bf16 bf16x8 __attribute__((ext_vector_type(8)));
typedef __bf16 bf16x4 __attribute__((ext_vector_type(4)));
typedef float  f32x4  __attribute__((ext_vector_type(4)));

#define MFMA16(A,B,C) __builtin_amdgcn_mfma_f32_16x16x32_bf16((A),(B),(C),0,0,0)
#define BARRIER() __builtin_amdgcn_s_barrier()
#define VMCNT0() asm volatile("s_waitcnt vmcnt(0)" ::: "memory")
#define VMCNT8() asm volatile("s_waitcnt vmcnt(8)" ::: "memory")

__device__ __forceinline__ void gload16(const void* g, void* l) {
  __builtin_amdgcn_global_load_lds(
      (__attribute__((address_space(1))) void*)(void*)g,
      (__attribute__((address_space(3))) void*)l, 16, 0, 0);
}

// ---------------- f32 -> bf16 elementwise ----------------
__global__ __launch_bounds__(256) void f32_to_bf16(const float* __restrict__ in,
                                                   bf16_t* __restrict__ out, size_t n8) {
  size_t i = (size_t)blockIdx.x * blockDim.x + threadIdx.x;
  size_t stride = (size_t)gridDim.x * blockDim.x;
  for (; i < n8; i += stride) {
    f32x4 a = *(const f32x4*)(in + i * 8);
    f32x4 b = *(const f32x4*)(in + i * 8 + 4);
    bf16x8 o;
#pragma unroll
    for (int j = 0; j < 4; ++j) { o[j] = (bf16_t)a[j]; o[4 + j] = (bf16_t)b[j]; }
    *(bf16x8*)(out + i * 8) = o;
  }
}

// ------------- W [K][N] f32 -> Wt [N][K] bf16: in-register 4x4 transpose -------------
// Coalesced f32x4 loads, 4x ds_write_b64, contiguous ds_read_b128 rows (no scalar LDS reads).
__global__ __launch_bounds__(256) void wtrans(const float* __restrict__ W,
                                              bf16_t* __restrict__ Wt, int K, int N) {
  __shared__ bf16_t t[64 * 68];  // [n][k], stride 68 (8B-aligned quad writes)
  const int k0 = blockIdx.x * 64, n0 = blockIdx.y * 64, tid = threadIdx.x;
  const int tn = tid & 15, tk = tid >> 4;  // 16 n-quads x 16 k-quads
  f32x4 v[4];
#pragma unroll
  for (int jj = 0; jj < 4; ++jj)
    v[jj] = *(const f32x4*)(W + (size_t)(k0 + 4 * tk + jj) * N + n0 + 4 * tn);
#pragma unroll
  for (int j = 0; j < 4; ++j) {
    bf16x4 o;
#pragma unroll
    for (int jj = 0; jj < 4; ++jj) o[jj] = (bf16_t)v[jj][j];
    *(bf16x4*)&t[(4 * tn + j) * 68 + 4 * tk] = o;
  }
  __syncthreads();
#pragma unroll
  for (int i = 0; i < 2; ++i) {
    int c = i * 256 + tid, rn = c >> 3, ck = (c & 7) * 8;
    bf16x8 o = *(const bf16x8*)&t[rn * 68 + ck];
    *(bf16x8*)(Wt + (size_t)(n0 + rn) * K + k0 + ck) = o;
  }
}

// ------------- v slice of qkv -> Vt[h][d][l]: in-register 4x4 transpose -------------
__global__ __launch_bounds__(256) void v_trans(const bf16_t* __restrict__ qkv,
                                               bf16_t* __restrict__ Vt) {
  __shared__ bf16_t t[128 * 68];  // [d][l], stride 68
  const int l0 = blockIdx.x * 64, h = blockIdx.y, tid = threadIdx.x;
  const int td = tid & 31, tl = tid >> 5;  // 32 d-quads x 8 l-quads (x2 iters)
#pragma unroll
  for (int it = 0; it < 2; ++it) {
    const int lq = tl + it * 8;  // l-quad 0..15
    bf16x4 v[4];
#pragma unroll
    for (int jj = 0; jj < 4; ++jj)
      v[jj] = *(const bf16x4*)(qkv + (size_t)(l0 + 4 * lq + jj) * (3 * DIMC) +
                               2 * DIMC + h * HD + 4 * td);
#pragma unroll
    for (int j = 0; j < 4; ++j) {
      bf16x4 o;
#pragma unroll
      for (int jj = 0; jj < 4; ++jj) o[jj] = v[jj][j];
      *(bf16x4*)&t[(4 * td + j) * 68 + 4 * lq] = o;
    }
  }
  __syncthreads();
#pragma unroll
  for (int i = 0; i < 4; ++i) {
    int c = i * 256 + tid, d = c >> 3, cl = (c & 7) * 8;
    bf16x8 o = *(const bf16x8*)&t[d * 68 + cl];
    *(bf16x8*)(Vt + ((size_t)h * HD + d) * L_C + l0 + cl) = o;
  }
}

// ================= 256x256 GEMM, counted-vmcnt 2-tile pipeline =================
// During tile k (reading buf k&1) stage tile k+2 INTO THE SAME BUFFER into regions
// already fully read: B region dead after phase 2 (barrier) -> stageB in phase 3;
// A region dead after phase 3 -> stageA in phase 4. Tile k+1's loads were issued a
// full tile earlier. Boundary wait = vmcnt(8): oldest 8 (tile k+1) landed, newest 8
// (tile k+2) stay in flight. Never drains to 0 in the main loop.
template <int OUT_BF16, int K>
__global__ __launch_bounds__(512, 1) void gemm8(const bf16_t* __restrict__ A,
                                                const bf16_t* __restrict__ Bt,
                                                const float* __restrict__ bias,
                                                bf16_t* __restrict__ Cb,
                                                float* __restrict__ Cf,
                                                int M, int N) {
  __shared__ __align__(16) char smem[131072];
  const int tid = threadIdx.x;
  const int wid = tid >> 6, lane = tid & 63;
  const int g = lane >> 4, r = lane & 15;
  const int wm = wid >> 2, wn = wid & 3;
  const int nb = gridDim.x * gridDim.y;
  const int bid = blockIdx.y * gridDim.x + blockIdx.x;
  const int swz = (bid & 7) * (nb >> 3) + (bid >> 3);
  const int bm = swz % gridDim.x, bn = swz / gridDim.x;
  const int row0 = bm * 256, col0 = bn * 256;

  auto stageA = [&](int buf, int half, int kt) {
#pragma unroll
    for (int i = 0; i < 2; ++i) {
      const int idx = i * 512 + tid;
      const int rl = idx >> 3, c = idx & 7;
      gload16(A + (size_t)(row0 + half * 128 + rl) * K + kt * 64 + ((c ^ (rl & 7)) << 3),
              smem + buf * 65536 + half * 16384 + (i * 512 + wid * 64) * 16);
    }
  };
  auto stageB = [&](int buf, int half, int kt) {
#pragma unroll
    for (int i = 0; i < 2; ++i) {
      const int idx = i * 512 + tid;
      const int rl = idx >> 3, c = idx & 7;
      gload16(Bt + (size_t)(col0 + half * 128 + rl) * K + kt * 64 + ((c ^ (rl & 7)) << 3),
              smem + buf * 65536 + 32768 + half * 16384 + (i * 512 + wid * 64) * 16);
    }
  };
  auto ldA = [&](int buf, int mi, int kk) {
    const int rh = mi * 16 + r;
    return *(const bf16x8*)(smem + buf * 65536 + wm * 16384 + rh * 128 +
                            (((kk * 4 + g) ^ (r & 7)) << 4));
  };
  auto ldB = [&](int buf, int ni, int kk) {
    const int rh = (wn & 1) * 64 + ni * 16 + r;
    return *(const bf16x8*)(smem + buf * 65536 + 32768 + (wn >> 1) * 16384 + rh * 128 +
                            (((kk * 4 + g) ^ (r & 7)) << 4));
  };

  f32x4 acc[8][4] = {};
  bf16x8 af[4][2], bfr[4][2];
  constexpr int nk = K / 64;

  // Prologue: tile0 -> buf0 (8 loads), tile1 -> buf1 (8 loads); wait tile0 only.
  stageA(0, 0, 0); stageA(0, 1, 0); stageB(0, 0, 0); stageB(0, 1, 0);
  stageA(1, 0, 1); stageA(1, 1, 1); stageB(1, 0, 1); stageB(1, 1, 1);
  VMCNT8();
  BARRIER();

  auto ktile = [&](int k, int cur) {
    const bool pf2 = (k + 2 < nk);
    // ---- phase 1: read af(mi0-3) + bfr(ni0-1); compute Q00
#pragma unroll
    for (int i = 0; i < 4; ++i)
#pragma unroll
      for (int kk = 0; kk < 2; ++kk) af[i][kk] = ldA(cur, i, kk);
#pragma unroll
    for (int j = 0; j < 2; ++j)
#pragma unroll
      for (int kk = 0; kk < 2; ++kk) bfr[j][kk] = ldB(cur, j, kk);
    BARRIER();
    __builtin_amdgcn_s_setprio(1);
#pragma unroll
    for (int i = 0; i < 4; ++i)
#pragma unroll
      for (int j = 0; j < 2; ++j)
#pragma unroll
        for (int kk = 0; kk < 2; ++kk)
          acc[i][j] = MFMA16(af[i][kk], bfr[j][kk], acc[i][j]);
    __builtin_amdgcn_s_setprio(0);
    BARRIER();
    // ---- phase 2: read bfr(ni2-3); compute Q01 (af mi0-3 live). B reads complete here.
#pragma unroll
    for (int j = 0; j < 2; ++j)
#pragma unroll
      for (int kk = 0; kk < 2; ++kk) bfr[2 + j][kk] = ldB(cur, 2 + j, kk);
    BARRIER();
    __builtin_amdgcn_s_setprio(1);
#pragma unroll
    for (int i = 0; i < 4; ++i)
#pragma unroll
      for (int j = 0; j < 2; ++j)
#pragma unroll
        for (int kk = 0; kk < 2; ++kk)
          acc[i][2 + j] = MFMA16(af[i][kk], bfr[2 + j][kk], acc[i][2 + j]);
    __builtin_amdgcn_s_setprio(0);
    BARRIER();
    // ---- phase 3: read af(mi4-7); stage B(k+2) into freed B region; compute Q11
#pragma unroll
    for (int i = 0; i < 4; ++i)
#pragma unroll
      for (int kk = 0; kk < 2; ++kk) af[i][kk] = ldA(cur, 4 + i, kk);
    if (pf2) { stageB(cur, 0, k + 2); stageB(cur, 1, k + 2); }
    BARRIER();
    __builtin_amdgcn_s_setprio(1);
#pragma unroll
    for (int i = 0; i < 4; ++i)
#pragma unroll
      for (int j = 0; j < 2; ++j)
#pragma unroll
        for (int kk = 0; kk < 2; ++kk)
          acc[4 + i][2 + j] = MFMA16(af[i][kk], bfr[2 + j][kk], acc[4 + i][2 + j]);
    __builtin_amdgcn_s_setprio(0);
    BARRIER();
    // ---- phase 4: stage A(k+2) into freed A region; compute Q10; counted boundary
    if (pf2) { stageA(cur, 0, k + 2); stageA(cur, 1, k + 2); }
    __builtin_amdgcn_s_setprio(1);
#pragma unroll
    for (int i = 0; i < 4; ++i)
#pragma unroll
      for (int j = 0; j < 2; ++j)
#pragma unroll
        for (int kk = 0; kk < 2; ++kk)
          acc[4 + i][j] = MFMA16(af[i][kk], bfr[j][kk], acc[4 + i][j]);
    __builtin_amdgcn_s_setprio(0);
    if (pf2) { VMCNT8(); } else { VMCNT0(); }  // tile k+1 landed; k+2 stays in flight
    BARRIER();
  };

  for (int kp = 0; kp < nk; kp += 2) { ktile(kp, 0); ktile(kp + 1, 1); }

#pragma unroll
  for (int mi = 0; mi < 8; ++mi)
#pragma unroll
    for (int ni = 0; ni < 4; ++ni)
#pragma unroll
      for (int p = 0; p < 4; ++p) {
        const int rr = row0 + wm * 128 + mi * 16 + 4 * g + p;
        const int cc = col0 + wn * 64 + ni * 16 + r;
        const float v = acc[mi][ni][p] + bias[cc];
        if (OUT_BF16) Cb[(size_t)rr * N + cc] = (bf16_t)v;
        else          Cf[(size_t)rr * N + cc] = v;
      }
}

// ---------------- RMSNorm(q,k) + RoPE (q,k rows stashed in LDS on pass 1) ----------------
__global__ __launch_bounds__(256) void norm_rope(const bf16_t* __restrict__ qkv,
                                                 const float* __restrict__ wq,
                                                 const float* __restrict__ wk,
                                                 const float* __restrict__ fcos,
                                                 const float* __restrict__ fsin,
                                                 bf16_t* __restrict__ Qo,
                                                 bf16_t* __restrict__ Ko) {
  __shared__ bf16_t qs[DIMC], ks_[DIMC];
  const int l = blockIdx.x, tid = threadIdx.x;
  const bf16_t* row = qkv + (size_t)l * (3 * DIMC);
  float sq = 0.f, sk = 0.f;
  for (int i = tid; i < DIMC / 8; i += 256) {
    bf16x8 a = *(const bf16x8*)(row + i * 8);
    bf16x8 b = *(const bf16x8*)(row + DIMC + i * 8);
    *(bf16x8*)&qs[i * 8] = a;
    *(bf16x8*)&ks_[i * 8] = b;
#pragma unroll
    for (int j = 0; j < 8; ++j) {
      float x = (float)a[j]; sq += x * x;
      float y = (float)b[j]; sk += y * y;
    }
  }
#pragma unroll
  for (int off = 32; off; off >>= 1) {
    sq += __shfl_xor(sq, off, 64);
    sk += __shfl_xor(sk, off, 64);
  }
  __shared__ float red[2][4];
  const int wid = tid >> 6, lane = tid & 63;
  if (!lane) { red[0][wid] = sq; red[1][wid] = sk; }
  __syncthreads();
  sq = red[0][0] + red[0][1] + red[0][2] + red[0][3];
  sk = red[1][0] + red[1][1] + red[1][2] + red[1][3];
  const float rq = rsqrtf(sq * (1.f / DIMC) + 1e-6f);
  const float rk = rsqrtf(sk * (1.f / DIMC) + 1e-6f);
  for (int i = tid; i < DIMC / 8; i += 256) {
    const int j0 = i * 8, h = j0 >> 7, d0 = j0 & 127;
    bf16x8 a = *(const bf16x8*)&qs[j0];   // same-thread stash, no barrier needed
    bf16x8 b = *(const bf16x8*)&ks_[j0];
    f32x4 cA = *(const f32x4*)(fcos + (size_t)l * HD + d0);
    f32x4 cB = *(const f32x4*)(fcos + (size_t)l * HD + d0 + 4);
    f32x4 sA = *(const f32x4*)(fsin + (size_t)l * HD + d0);
    f32x4 sB = *(const f32x4*)(fsin + (size_t)l * HD + d0 + 4);
    f32x4 wqA = *(const f32x4*)(wq + j0), wqB = *(const f32x4*)(wq + j0 + 4);
    f32x4 wkA = *(const f32x4*)(wk + j0), wkB = *(const f32x4*)(wk + j0 + 4);
    float cc[8], ss[8], qn[8], kn[8];
#pragma unroll
    for (int j = 0; j < 4; ++j) {
      cc[j] = cA[j]; cc[4 + j] = cB[j];
      ss[j] = sA[j]; ss[4 + j] = sB[j];
      qn[j] = (float)a[j] * rq * wqA[j];
      qn[4 + j] = (float)a[4 + j] * rq * wqB[j];
      kn[j] = (float)b[j] * rk * wkA[j];
      kn[4 + j] = (float)b[4 + j] * rk * wkB[j];
    }
    bf16x8 oq, ok;
#pragma unroll
    for (int p = 0; p < 4; ++p) {
      const float c = cc[2 * p], s = ss[2 * p + 1];
      oq[2 * p]     = (bf16_t)(qn[2 * p] * c - qn[2 * p + 1] * s);
      oq[2 * p + 1] = (bf16_t)(qn[2 * p] * s + qn[2 * p + 1] * c);
      ok[2 * p]     = (bf16_t)(kn[2 * p] * c - kn[2 * p + 1] * s);
      ok[2 * p + 1] = (bf16_t)(kn[2 * p] * s + kn[2 * p + 1] * c);
    }
    *(bf16x8*)(Qo + ((size_t)h * L_C + l) * HD + d0) = oq;
    *(bf16x8*)(Ko + ((size_t)h * L_C + l) * HD + d0) = ok;
  }
}

// ---------------- flash attention: per (head, 128 q rows) ----------------
__global__ __launch_bounds__(256, 2) void attn(const bf16_t* __restrict__ Q,
                                               const bf16_t* __restrict__ Kg,
                                               const bf16_t* __restrict__ Vt,
                                               bf16_t* __restrict__ O) {
  __shared__ bf16_t k_lds[64 * HD];
  __shared__ bf16_t v_lds[HD * 64];
  __shared__ bf16_t p_lds[4][2][16 * 72];
  const int tid = threadIdx.x, wid = tid >> 6, lane = tid & 63;
  const int g = lane >> 4, r = lane & 15;
  const int bid = blockIdx.x;
  const int grp = bid & 7, inner = bid >> 3;
  const int h = (inner >> 4) * 8 + grp;
  const int q0 = (inner & 15) * 128 + wid * 32;
  bf16x8 qf[2][4];
#pragma unroll
  for (int rg = 0; rg < 2; ++rg) {
    const bf16_t* qrow = Q + ((size_t)h * L_C + q0 + rg * 16 + r) * HD;
#pragma unroll
    for (int ks = 0; ks < 4; ++ks) qf[rg][ks] = *(const bf16x8*)(qrow + ks * 32 + g * 8);
  }
  f32x4 oacc[2][8] = {};
  float m_i[2][4], l_i[2][4];
#pragma unroll
  for (int rg = 0; rg < 2; ++rg)
#pragma unroll
    for (int p = 0; p < 4; ++p) { m_i[rg][p] = -1e30f; l_i[rg][p] = 0.f; }
  const float scale = 0.08838834764831845f;

  bf16x8 kreg[4], vreg[4];
  auto load_kv = [&](int kv0) {
#pragma unroll
    for (int i = 0; i < 4; ++i) {
      const int c = i * 256 + tid;
      const int krow = c >> 4, kcb = c & 15;
      kreg[i] = *(const bf16x8*)(Kg + ((size_t)h * L_C + kv0 + krow) * HD + kcb * 8);
      const int vrow = c >> 3, vcb = c & 7;
      vreg[i] = *(const bf16x8*)(Vt + ((size_t)h * HD + vrow) * L_C + kv0 + vcb * 8);
    }
  };
  load_kv(0);

  for (int kv0 = 0; kv0 < L_C; kv0 += 64) {
    __syncthreads();
#pragma unroll
    for (int i = 0; i < 4; ++i) {
      const int c = i * 256 + tid;
      const int krow = c >> 4, kcb = c & 15;
      *(bf16x8*)((char*)k_lds + krow * 256 + ((kcb * 16) ^ ((krow & 7) << 4))) = kreg[i];
      const int vrow = c >> 3, vcb = c & 7;
      *(bf16x8*)((char*)v_lds + vrow * 128 + ((vcb * 16) ^ ((vrow & 7) << 4))) = vreg[i];
    }
    if (kv0 + 64 < L_C) load_kv(kv0 + 64);
    __syncthreads();

    float pv[2][4][4];
    __builtin_amdgcn_s_setprio(1);
#pragma unroll
    for (int nf = 0; nf < 4; ++nf) {
      f32x4 s0 = {0.f, 0.f, 0.f, 0.f}, s1 = {0.f, 0.f, 0.f, 0.f};
      const int key = nf * 16 + r;
#pragma unroll
      for (int ks = 0; ks < 4; ++ks) {
        bf16x8 kf = *(const bf16x8*)((const char*)k_lds + key * 256 +
                                     ((ks * 64 + g * 16) ^ ((key & 7) << 4)));
        s0 = MFMA16(qf[0][ks], kf, s0);
        s1 = MFMA16(qf[1][ks], kf, s1);
      }
#pragma unroll
      for (int p = 0; p < 4; ++p) { pv[0][nf][p] = s0[p] * scale; pv[1][nf][p] = s1[p] * scale; }
    }
    __builtin_amdgcn_s_setprio(0);
#pragma unroll
    for (int rg = 0; rg < 2; ++rg) {
      float mnew[4];
#pragma unroll
      for (int p = 0; p < 4; ++p)
        mnew[p] = fmaxf(fmaxf(pv[rg][0][p], pv[rg][1][p]), fmaxf(pv[rg][2][p], pv[rg][3][p]));
#pragma unroll
      for (int m = 1; m < 16; m <<= 1)
#pragma unroll
        for (int p = 0; p < 4; ++p) mnew[p] = fmaxf(mnew[p], __shfl_xor(mnew[p], m, 64));
      float alpha[4], rsum[4];
#pragma unroll
      for (int p = 0; p < 4; ++p) {
        const float mi = fmaxf(m_i[rg][p], mnew[p]);
        alpha[p] = __expf(m_i[rg][p] - mi);
        m_i[rg][p] = mi;
        rsum[p] = 0.f;
      }
#pragma unroll
      for (int nf = 0; nf < 4; ++nf)
#pragma unroll
        for (int p = 0; p < 4; ++p) {
          pv[rg][nf][p] = __expf(pv[rg][nf][p] - m_i[rg][p]);
          rsum[p] += pv[rg][nf][p];
        }
#pragma unroll
      for (int nf = 0; nf < 4; ++nf)
#pragma unroll
        for (int p = 0; p < 4; ++p)
          p_lds[wid][rg][(4 * g + p) * 72 + nf * 16 + r] = (bf16_t)pv[rg][nf][p];
#pragma unroll
      for (int m = 1; m < 16; m <<= 1)
#pragma unroll
        for (int p = 0; p < 4; ++p) rsum[p] += __shfl_xor(rsum[p], m, 64);
#pragma unroll
      for (int p = 0; p < 4; ++p) l_i[rg][p] = l_i[rg][p] * alpha[p] + rsum[p];
#pragma unroll
      for (int nf = 0; nf < 8; ++nf)
#pragma unroll
        for (int p = 0; p < 4; ++p) oacc[rg][nf][p] *= alpha[p];
    }
    bf16x8 pf0[2], pf1[2];
#pragma unroll
    for (int rg = 0; rg < 2; ++rg) {
      pf0[rg] = *(const bf16x8*)&p_lds[wid][rg][r * 72 + 8 * g];
      pf1[rg] = *(const bf16x8*)&p_lds[wid][rg][r * 72 + 32 + 8 * g];
    }
    __builtin_amdgcn_s_setprio(1);
#pragma unroll
    for (int nf = 0; nf < 8; ++nf) {
      const int d = nf * 16 + r;
      bf16x8 vf0 = *(const bf16x8*)((const char*)v_lds + d * 128 +
                                    ((g * 16) ^ ((d & 7) << 4)));
      bf16x8 vf1 = *(const bf16x8*)((const char*)v_lds + d * 128 +
                                    ((64 + g * 16) ^ ((d & 7) << 4)));
#pragma unroll
      for (int rg = 0; rg < 2; ++rg) {
        oacc[rg][nf] = MFMA16(pf0[rg], vf0, oacc[rg][nf]);
        oacc[rg][nf] = MFMA16(pf1[rg], vf1, oacc[rg][nf]);
      }
    }
    __builtin_amdgcn_s_setprio(0);
  }
#pragma unroll
  for (int rg = 0; rg < 2; ++rg)
#pragma unroll
    for (int p = 0; p < 4; ++p) {
      const float inv = 1.f / l_i[rg][p];
      const int rowg = q0 + rg * 16 + 4 * g + p;
#pragma unroll
      for (int nf = 0; nf < 8; ++nf) {
        const int d = nf * 16 + r;
        O[(size_t)rowg * DIMC + h * HD + d] = (bf16_t)(oacc[rg][nf][p] * inv);
      }
    }
}

// ---------------- launch ----------------
extern "C" void kernel_launch(void* const* d_in, const int* in_sizes, int n_in,
                              void* d_out, int out_size, void* d_ws, size_t ws_size,
                              hipStream_t stream) {
  const float* hidden = (const float*)d_in[0];
  const float* fcos   = (const float*)d_in[1];
  const float* fsin   = (const float*)d_in[2];
  const float* Wqkv   = (const float*)d_in[3];
  const float* bqkv   = (const float*)d_in[4];
  const float* wnq    = (const float*)d_in[5];
  const float* wnk    = (const float*)d_in[6];
  const float* Wout   = (const float*)d_in[7];
  const float* bout   = (const float*)d_in[8];
  float* out = (float*)d_out;

  char* ws = (char*)d_ws;
  size_t off = 0;
  auto alloc = [&](size_t bytes) {
    void* p = ws + off;
    off += (bytes + 255) & ~(size_t)255;
    return p;
  };
  bf16_t* X   = (bf16_t*)alloc((size_t)L_C * DIMC * 2);
  bf16_t* WQT = (bf16_t*)alloc((size_t)3 * DIMC * DIMC * 2);
  bf16_t* WOT = (bf16_t*)alloc((size_t)DIMC * DIMC * 2);
  bf16_t* QKV = (bf16_t*)alloc((size_t)L_C * 3 * DIMC * 2);
  bf16_t* Qb  = (bf16_t*)alloc((size_t)L_C * DIMC * 2);
  bf16_t* Kb  = (bf16_t*)alloc((size_t)L_C * DIMC * 2);
  bf16_t* VT  = (bf16_t*)alloc((size_t)L_C * DIMC * 2);
  bf16_t* Ob  = X;  // X dead after gemm1; reuse for attention output

  f32_to_bf16<<<2048, 256, 0, stream>>>(hidden, X, (size_t)L_C * DIMC / 8);
  wtrans<<<dim3(DIMC / 64, 3 * DIMC / 64), 256, 0, stream>>>(Wqkv, WQT, DIMC, 3 * DIMC);
  wtrans<<<dim3(DIMC / 64, DIMC / 64), 256, 0, stream>>>(Wout, WOT, DIMC, DIMC);
  gemm8<1, DIMC><<<dim3(L_C / 256, 3 * DIMC / 256), 512, 0, stream>>>(
      X, WQT, bqkv, QKV, nullptr, L_C, 3 * DIMC);
  norm_rope<<<L_C, 256, 0, stream>>>(QKV, wnq, wnk, fcos, fsin, Qb, Kb);
  v_trans<<<dim3(L_C / 64, NHEADS), 256, 0, stream>>>(QKV, VT);
  attn<<<(L_C / 128) * NHEADS, 256, 0, stream>>>(Qb, Kb, VT, Ob);
  gemm8<0, DIMC><<<dim3(L_C / 256, DIMC / 256), 512, 0, stream>>>(
      Ob, WOT, bout, nullptr, out, L_C, DIMC);
}

// Round 7
// 777.035 us; speedup vs baseline: 1.3197x; 1.0345x over previous
//
#include <hip/hip_runtime.h>
#include <cstdint>
#include <cstddef>

#define L_C   2048
#define DIMC  5120
#define HD    128
#define NHEADS 40

typedef __bf16 bf16_t;
typedef __bf16 bf16x8 __attribute__((ext_vector_type(8)));
typedef __bf16 bf16x4 __attribute__((ext_vector_type(4)));
typedef float  f32x4  __attribute__((ext_vector_type(4)));

#define MFMA16(A,B,C) __builtin_amdgcn_mfma_f32_16x16x32_bf16((A),(B),(C),0,0,0)
#define BARRIER() __builtin_amdgcn_s_barrier()
#define LGKM0()  asm volatile("s_waitcnt lgkmcnt(0)" ::: "memory")
#define VMCNT0() asm volatile("s_waitcnt vmcnt(0)" ::: "memory")
#define VMCNT4() asm volatile("s_waitcnt vmcnt(4)" ::: "memory")
#define VMCNT6() asm volatile("s_waitcnt vmcnt(6)" ::: "memory")
#define VMCNT8() asm volatile("s_waitcnt vmcnt(8)" ::: "memory")

__device__ __forceinline__ void gload16(const void* g, void* l) {
  __builtin_amdgcn_global_load_lds(
      (__attribute__((address_space(1))) void*)(void*)g,
      (__attribute__((address_space(3))) void*)l, 16, 0, 0);
}

// ---------------- f32 -> bf16 elementwise ----------------
__global__ __launch_bounds__(256) void f32_to_bf16(const float* __restrict__ in,
                                                   bf16_t* __restrict__ out, size_t n8) {
  size_t i = (size_t)blockIdx.x * blockDim.x + threadIdx.x;
  size_t stride = (size_t)gridDim.x * blockDim.x;
  for (; i < n8; i += stride) {
    f32x4 a = *(const f32x4*)(in + i * 8);
    f32x4 b = *(const f32x4*)(in + i * 8 + 4);
    bf16x8 o;
#pragma unroll
    for (int j = 0; j < 4; ++j) { o[j] = (bf16_t)a[j]; o[4 + j] = (bf16_t)b[j]; }
    *(bf16x8*)(out + i * 8) = o;
  }
}

// ------------- W [K][N] f32 -> Wt [N][K] bf16: in-register 4x4 transpose -------------
__global__ __launch_bounds__(256) void wtrans(const float* __restrict__ W,
                                              bf16_t* __restrict__ Wt, int K, int N) {
  __shared__ bf16_t t[64 * 68];
  const int k0 = blockIdx.x * 64, n0 = blockIdx.y * 64, tid = threadIdx.x;
  const int tn = tid & 15, tk = tid >> 4;
  f32x4 v[4];
#pragma unroll
  for (int jj = 0; jj < 4; ++jj)
    v[jj] = *(const f32x4*)(W + (size_t)(k0 + 4 * tk + jj) * N + n0 + 4 * tn);
#pragma unroll
  for (int j = 0; j < 4; ++j) {
    bf16x4 o;
#pragma unroll
    for (int jj = 0; jj < 4; ++jj) o[jj] = (bf16_t)v[jj][j];
    *(bf16x4*)&t[(4 * tn + j) * 68 + 4 * tk] = o;
  }
  __syncthreads();
#pragma unroll
  for (int i = 0; i < 2; ++i) {
    int c = i * 256 + tid, rn = c >> 3, ck = (c & 7) * 8;
    bf16x8 o = *(const bf16x8*)&t[rn * 68 + ck];
    *(bf16x8*)(Wt + (size_t)(n0 + rn) * K + k0 + ck) = o;
  }
}

// ------------- v slice of qkv -> Vt[h][d][l]: in-register 4x4 transpose -------------
__global__ __launch_bounds__(256) void v_trans(const bf16_t* __restrict__ qkv,
                                               bf16_t* __restrict__ Vt) {
  __shared__ bf16_t t[128 * 68];
  const int l0 = blockIdx.x * 64, h = blockIdx.y, tid = threadIdx.x;
  const int td = tid & 31, tl = tid >> 5;
#pragma unroll
  for (int it = 0; it < 2; ++it) {
    const int lq = tl + it * 8;
    bf16x4 v[4];
#pragma unroll
    for (int jj = 0; jj < 4; ++jj)
      v[jj] = *(const bf16x4*)(qkv + (size_t)(l0 + 4 * lq + jj) * (3 * DIMC) +
                               2 * DIMC + h * HD + 4 * td);
#pragma unroll
    for (int j = 0; j < 4; ++j) {
      bf16x4 o;
#pragma unroll
      for (int jj = 0; jj < 4; ++jj) o[jj] = v[jj][j];
      *(bf16x4*)&t[(4 * td + j) * 68 + 4 * lq] = o;
    }
  }
  __syncthreads();
#pragma unroll
  for (int i = 0; i < 4; ++i) {
    int c = i * 256 + tid, d = c >> 3, cl = (c & 7) * 8;
    bf16x8 o = *(const bf16x8*)&t[d * 68 + cl];
    *(bf16x8*)(Vt + ((size_t)h * HD + d) * L_C + l0 + cl) = o;
  }
}

// ================= 256x256 GEMM, fine-interleaved 8-phase (m201-style) =================
// One half-tile staged per phase, counted vmcnt(4)/(6) only at the two tile boundaries.
// Race ledger (regions freed by barrier-separated last reads):
//  ph1 stage Ah1(t+1)->b1 [b1-A freed ph7 prev]   ph5 stage Bh1(t+2)->b0 [b0-B freed ph2]
//  ph3 stage Bh0(t+2)->b0 [b0-B freed ph2]        ph6 stage Ah1(t+2)->b0 [b0-A freed ph3]
//  ph4 stage Ah0(t+2)->b0 [b0-A freed ph3]        ph7 stage Bh0(t+3)->b1 [b1-B freed ph6]
//  ph8 stage Bh1(t+3)+Ah0(t+3)->b1 [b1-A freed ph7]
//  WAIT-A end ph4: vmcnt(4) => A(t+1),B(t+1) landed (2 htiles in flight)
//  WAIT-B end ph8: vmcnt(6) => A(t+2),B(t+2) landed (3 htiles in flight)
template <int OUT_BF16, int K>
__global__ __launch_bounds__(512, 1) void gemm8(const bf16_t* __restrict__ A,
                                                const bf16_t* __restrict__ Bt,
                                                const float* __restrict__ bias,
                                                bf16_t* __restrict__ Cb,
                                                float* __restrict__ Cf,
                                                int M, int N) {
  __shared__ __align__(16) char smem[131072];
  const int tid = threadIdx.x;
  const int wid = tid >> 6, lane = tid & 63;
  const int g = lane >> 4, r = lane & 15;
  const int wm = wid >> 2, wn = wid & 3;
  const int nb = gridDim.x * gridDim.y;
  const int bid = blockIdx.y * gridDim.x + blockIdx.x;
  const int swz = (bid & 7) * (nb >> 3) + (bid >> 3);
  const int bm = swz % gridDim.x, bn = swz / gridDim.x;
  const int row0 = bm * 256, col0 = bn * 256;

  auto stageA = [&](int buf, int half, int kt) {
#pragma unroll
    for (int i = 0; i < 2; ++i) {
      const int idx = i * 512 + tid;
      const int rl = idx >> 3, c = idx & 7;
      gload16(A + (size_t)(row0 + half * 128 + rl) * K + kt * 64 + ((c ^ (rl & 7)) << 3),
              smem + buf * 65536 + half * 16384 + (i * 512 + wid * 64) * 16);
    }
  };
  auto stageB = [&](int buf, int half, int kt) {
#pragma unroll
    for (int i = 0; i < 2; ++i) {
      const int idx = i * 512 + tid;
      const int rl = idx >> 3, c = idx & 7;
      gload16(Bt + (size_t)(col0 + half * 128 + rl) * K + kt * 64 + ((c ^ (rl & 7)) << 3),
              smem + buf * 65536 + 32768 + half * 16384 + (i * 512 + wid * 64) * 16);
    }
  };
  auto ldA = [&](int buf, int mi, int kk) {
    const int rh = mi * 16 + r;
    return *(const bf16x8*)(smem + buf * 65536 + wm * 16384 + rh * 128 +
                            (((kk * 4 + g) ^ (r & 7)) << 4));
  };
  auto ldB = [&](int buf, int ni, int kk) {
    const int rh = (wn & 1) * 64 + ni * 16 + r;
    return *(const bf16x8*)(smem + buf * 65536 + 32768 + (wn >> 1) * 16384 + rh * 128 +
                            (((kk * 4 + g) ^ (r & 7)) << 4));
  };

  f32x4 acc[8][4] = {};
  bf16x8 af[4][2], bfr[4][2];
  constexpr int nk = K / 64;

  // Prologue: t0 -> buf0 (8 loads), t1 -> buf1 (8 loads); t0 landed, t1 in flight.
  stageA(0, 0, 0); stageA(0, 1, 0); stageB(0, 0, 0); stageB(0, 1, 0);
  stageA(1, 0, 1); stageA(1, 1, 1); stageB(1, 0, 1); stageB(1, 1, 1);
  VMCNT8();
  BARRIER();

  for (int t = 0; t < nk; t += 2) {
    const bool first = (t == 0);
    const bool pf2 = (t + 2 < nk);   // pf3 == pf2 except t=nk-2 where both false... t=nk-4: both true
    const bool pf3 = (t + 3 < nk);
    // ======== tile t (buf0) ========
    // ---- ph1: reads af0-3,bfr0-1; stage Ah1(t+1)->b1; MFMA Q00
#pragma unroll
    for (int i = 0; i < 4; ++i)
#pragma unroll
      for (int kk = 0; kk < 2; ++kk) af[i][kk] = ldA(0, i, kk);
#pragma unroll
    for (int j = 0; j < 2; ++j)
#pragma unroll
      for (int kk = 0; kk < 2; ++kk) bfr[j][kk] = ldB(0, j, kk);
    if (!first) stageA(1, 1, t + 1);
    BARRIER(); LGKM0();
    __builtin_amdgcn_s_setprio(1);
#pragma unroll
    for (int i = 0; i < 4; ++i)
#pragma unroll
      for (int j = 0; j < 2; ++j)
#pragma unroll
        for (int kk = 0; kk < 2; ++kk) acc[i][j] = MFMA16(af[i][kk], bfr[j][kk], acc[i][j]);
    __builtin_amdgcn_s_setprio(0);
    BARRIER();
    // ---- ph2: reads bfr2-3; MFMA Q01
#pragma unroll
    for (int j = 0; j < 2; ++j)
#pragma unroll
      for (int kk = 0; kk < 2; ++kk) bfr[2 + j][kk] = ldB(0, 2 + j, kk);
    BARRIER(); LGKM0();
    __builtin_amdgcn_s_setprio(1);
#pragma unroll
    for (int i = 0; i < 4; ++i)
#pragma unroll
      for (int j = 0; j < 2; ++j)
#pragma unroll
        for (int kk = 0; kk < 2; ++kk) acc[i][2 + j] = MFMA16(af[i][kk], bfr[2 + j][kk], acc[i][2 + j]);
    __builtin_amdgcn_s_setprio(0);
    BARRIER();
    // ---- ph3: reads af4-7; stage Bh0(t+2)->b0; MFMA Q11
#pragma unroll
    for (int i = 0; i < 4; ++i)
#pragma unroll
      for (int kk = 0; kk < 2; ++kk) af[i][kk] = ldA(0, 4 + i, kk);
    if (pf2) stageB(0, 0, t + 2);
    BARRIER(); LGKM0();
    __builtin_amdgcn_s_setprio(1);
#pragma unroll
    for (int i = 0; i < 4; ++i)
#pragma unroll
      for (int j = 0; j < 2; ++j)
#pragma unroll
        for (int kk = 0; kk < 2; ++kk) acc[4 + i][2 + j] = MFMA16(af[i][kk], bfr[2 + j][kk], acc[4 + i][2 + j]);
    __builtin_amdgcn_s_setprio(0);
    BARRIER();
    // ---- ph4: stage Ah0(t+2)->b0; MFMA Q10; WAIT-A
    if (pf2) stageA(0, 0, t + 2);
    BARRIER();
    __builtin_amdgcn_s_setprio(1);
#pragma unroll
    for (int i = 0; i < 4; ++i)
#pragma unroll
      for (int j = 0; j < 2; ++j)
#pragma unroll
        for (int kk = 0; kk < 2; ++kk) acc[4 + i][j] = MFMA16(af[i][kk], bfr[j][kk], acc[4 + i][j]);
    __builtin_amdgcn_s_setprio(0);
    if (pf2) { VMCNT4(); } else { VMCNT0(); }
    BARRIER();
    // ======== tile t+1 (buf1) ========
    // ---- ph5: reads af0-3,bfr0-1; stage Bh1(t+2)->b0; MFMA Q00
#pragma unroll
    for (int i = 0; i < 4; ++i)
#pragma unroll
      for (int kk = 0; kk < 2; ++kk) af[i][kk] = ldA(1, i, kk);
#pragma unroll
    for (int j = 0; j < 2; ++j)
#pragma unroll
      for (int kk = 0; kk < 2; ++kk) bfr[j][kk] = ldB(1, j, kk);
    if (pf2) stageB(0, 1, t + 2);
    BARRIER(); LGKM0();
    __builtin_amdgcn_s_setprio(1);
#pragma unroll
    for (int i = 0; i < 4; ++i)
#pragma unroll
      for (int j = 0; j < 2; ++j)
#pragma unroll
        for (int kk = 0; kk < 2; ++kk) acc[i][j] = MFMA16(af[i][kk], bfr[j][kk], acc[i][j]);
    __builtin_amdgcn_s_setprio(0);
    BARRIER();
    // ---- ph6: reads bfr2-3; stage Ah1(t+2)->b0; MFMA Q01
#pragma unroll
    for (int j = 0; j < 2; ++j)
#pragma unroll
      for (int kk = 0; kk < 2; ++kk) bfr[2 + j][kk] = ldB(1, 2 + j, kk);
    if (pf2) stageA(0, 1, t + 2);
    BARRIER(); LGKM0();
    __builtin_amdgcn_s_setprio(1);
#pragma unroll
    for (int i = 0; i < 4; ++i)
#pragma unroll
      for (int j = 0; j < 2; ++j)
#pragma unroll
        for (int kk = 0; kk < 2; ++kk) acc[i][2 + j] = MFMA16(af[i][kk], bfr[2 + j][kk], acc[i][2 + j]);
    __builtin_amdgcn_s_setprio(0);
    BARRIER();
    // ---- ph7: reads af4-7; stage Bh0(t+3)->b1; MFMA Q11
#pragma unroll
    for (int i = 0; i < 4; ++i)
#pragma unroll
      for (int kk = 0; kk < 2; ++kk) af[i][kk] = ldA(1, 4 + i, kk);
    if (pf3) stageB(1, 0, t + 3);
    BARRIER(); LGKM0();
    __builtin_amdgcn_s_setprio(1);
#pragma unroll
    for (int i = 0; i < 4; ++i)
#pragma unroll
      for (int j = 0; j < 2; ++j)
#pragma unroll
        for (int kk = 0; kk < 2; ++kk) acc[4 + i][2 + j] = MFMA16(af[i][kk], bfr[2 + j][kk], acc[4 + i][2 + j]);
    __builtin_amdgcn_s_setprio(0);
    BARRIER();
    // ---- ph8: stages Bh1(t+3),Ah0(t+3)->b1; MFMA Q10; WAIT-B
    if (pf3) { stageB(1, 1, t + 3); stageA(1, 0, t + 3); }
    BARRIER();
    __builtin_amdgcn_s_setprio(1);
#pragma unroll
    for (int i = 0; i < 4; ++i)
#pragma unroll
      for (int j = 0; j < 2; ++j)
#pragma unroll
        for (int kk = 0; kk < 2; ++kk) acc[4 + i][j] = MFMA16(af[i][kk], bfr[j][kk], acc[4 + i][j]);
    __builtin_amdgcn_s_setprio(0);
    if (pf2) { VMCNT6(); } else { VMCNT0(); }
    BARRIER();
  }

#pragma unroll
  for (int mi = 0; mi < 8; ++mi)
#pragma unroll
    for (int ni = 0; ni < 4; ++ni)
#pragma unroll
      for (int p = 0; p < 4; ++p) {
        const int rr = row0 + wm * 128 + mi * 16 + 4 * g + p;
        const int cc = col0 + wn * 64 + ni * 16 + r;
        const float v = acc[mi][ni][p] + bias[cc];
        if (OUT_BF16) Cb[(size_t)rr * N + cc] = (bf16_t)v;
        else          Cf[(size_t)rr * N + cc] = v;
      }
}

// ---------------- RMSNorm(q,k) + RoPE (q,k rows stashed in LDS on pass 1) ----------------
__global__ __launch_bounds__(256) void norm_rope(const bf16_t* __restrict__ qkv,
                                                 const float* __restrict__ wq,
                                                 const float* __restrict__ wk,
                                                 const float* __restrict__ fcos,
                                                 const float* __restrict__ fsin,
                                                 bf16_t* __restrict__ Qo,
                                                 bf16_t* __restrict__ Ko) {
  __shared__ bf16_t qs[DIMC], ks_[DIMC];
  const int l = blockIdx.x, tid = threadIdx.x;
  const bf16_t* row = qkv + (size_t)l * (3 * DIMC);
  float sq = 0.f, sk = 0.f;
  for (int i = tid; i < DIMC / 8; i += 256) {
    bf16x8 a = *(const bf16x8*)(row + i * 8);
    bf16x8 b = *(const bf16x8*)(row + DIMC + i * 8);
    *(bf16x8*)&qs[i * 8] = a;
    *(bf16x8*)&ks_[i * 8] = b;
#pragma unroll
    for (int j = 0; j < 8; ++j) {
      float x = (float)a[j]; sq += x * x;
      float y = (float)b[j]; sk += y * y;
    }
  }
#pragma unroll
  for (int off = 32; off; off >>= 1) {
    sq += __shfl_xor(sq, off, 64);
    sk += __shfl_xor(sk, off, 64);
  }
  __shared__ float red[2][4];
  const int wid = tid >> 6, lane = tid & 63;
  if (!lane) { red[0][wid] = sq; red[1][wid] = sk; }
  __syncthreads();
  sq = red[0][0] + red[0][1] + red[0][2] + red[0][3];
  sk = red[1][0] + red[1][1] + red[1][2] + red[1][3];
  const float rq = rsqrtf(sq * (1.f / DIMC) + 1e-6f);
  const float rk = rsqrtf(sk * (1.f / DIMC) + 1e-6f);
  for (int i = tid; i < DIMC / 8; i += 256) {
    const int j0 = i * 8, h = j0 >> 7, d0 = j0 & 127;
    bf16x8 a = *(const bf16x8*)&qs[j0];
    bf16x8 b = *(const bf16x8*)&ks_[j0];
    f32x4 cA = *(const f32x4*)(fcos + (size_t)l * HD + d0);
    f32x4 cB = *(const f32x4*)(fcos + (size_t)l * HD + d0 + 4);
    f32x4 sA = *(const f32x4*)(fsin + (size_t)l * HD + d0);
    f32x4 sB = *(const f32x4*)(fsin + (size_t)l * HD + d0 + 4);
    f32x4 wqA = *(const f32x4*)(wq + j0), wqB = *(const f32x4*)(wq + j0 + 4);
    f32x4 wkA = *(const f32x4*)(wk + j0), wkB = *(const f32x4*)(wk + j0 + 4);
    float cc[8], ss[8], qn[8], kn[8];
#pragma unroll
    for (int j = 0; j < 4; ++j) {
      cc[j] = cA[j]; cc[4 + j] = cB[j];
      ss[j] = sA[j]; ss[4 + j] = sB[j];
      qn[j] = (float)a[j] * rq * wqA[j];
      qn[4 + j] = (float)a[4 + j] * rq * wqB[j];
      kn[j] = (float)b[j] * rk * wkA[j];
      kn[4 + j] = (float)b[4 + j] * rk * wkB[j];
    }
    bf16x8 oq, ok;
#pragma unroll
    for (int p = 0; p < 4; ++p) {
      const float c = cc[2 * p], s = ss[2 * p + 1];
      oq[2 * p]     = (bf16_t)(qn[2 * p] * c - qn[2 * p + 1] * s);
      oq[2 * p + 1] = (bf16_t)(qn[2 * p] * s + qn[2 * p + 1] * c);
      ok[2 * p]     = (bf16_t)(kn[2 * p] * c - kn[2 * p + 1] * s);
      ok[2 * p + 1] = (bf16_t)(kn[2 * p] * s + kn[2 * p + 1] * c);
    }
    *(bf16x8*)(Qo + ((size_t)h * L_C + l) * HD + d0) = oq;
    *(bf16x8*)(Ko + ((size_t)h * L_C + l) * HD + d0) = ok;
  }
}

// ---------------- flash attention: per (head, 128 q rows) ----------------
__global__ __launch_bounds__(256, 2) void attn(const bf16_t* __restrict__ Q,
                                               const bf16_t* __restrict__ Kg,
                                               const bf16_t* __restrict__ Vt,
                                               bf16_t* __restrict__ O) {
  __shared__ bf16_t k_lds[64 * HD];
  __shared__ bf16_t v_lds[HD * 64];
  __shared__ bf16_t p_lds[4][2][16 * 72];
  const int tid = threadIdx.x, wid = tid >> 6, lane = tid & 63;
  const int g = lane >> 4, r = lane & 15;
  const int bid = blockIdx.x;
  const int grp = bid & 7, inner = bid >> 3;
  const int h = (inner >> 4) * 8 + grp;
  const int q0 = (inner & 15) * 128 + wid * 32;
  bf16x8 qf[2][4];
#pragma unroll
  for (int rg = 0; rg < 2; ++rg) {
    const bf16_t* qrow = Q + ((size_t)h * L_C + q0 + rg * 16 + r) * HD;
#pragma unroll
    for (int ks = 0; ks < 4; ++ks) qf[rg][ks] = *(const bf16x8*)(qrow + ks * 32 + g * 8);
  }
  f32x4 oacc[2][8] = {};
  float m_i[2][4], l_i[2][4];
#pragma unroll
  for (int rg = 0; rg < 2; ++rg)
#pragma unroll
    for (int p = 0; p < 4; ++p) { m_i[rg][p] = -1e30f; l_i[rg][p] = 0.f; }
  const float scale = 0.08838834764831845f;

  bf16x8 kreg[4], vreg[4];
  auto load_kv = [&](int kv0) {
#pragma unroll
    for (int i = 0; i < 4; ++i) {
      const int c = i * 256 + tid;
      const int krow = c >> 4, kcb = c & 15;
      kreg[i] = *(const bf16x8*)(Kg + ((size_t)h * L_C + kv0 + krow) * HD + kcb * 8);
      const int vrow = c >> 3, vcb = c & 7;
      vreg[i] = *(const bf16x8*)(Vt + ((size_t)h * HD + vrow) * L_C + kv0 + vcb * 8);
    }
  };
  load_kv(0);

  for (int kv0 = 0; kv0 < L_C; kv0 += 64) {
    __syncthreads();
#pragma unroll
    for (int i = 0; i < 4; ++i) {
      const int c = i * 256 + tid;
      const int krow = c >> 4, kcb = c & 15;
      *(bf16x8*)((char*)k_lds + krow * 256 + ((kcb * 16) ^ ((krow & 7) << 4))) = kreg[i];
      const int vrow = c >> 3, vcb = c & 7;
      *(bf16x8*)((char*)v_lds + vrow * 128 + ((vcb * 16) ^ ((vrow & 7) << 4))) = vreg[i];
    }
    if (kv0 + 64 < L_C) load_kv(kv0 + 64);
    __syncthreads();

    float pv[2][4][4];
    __builtin_amdgcn_s_setprio(1);
#pragma unroll
    for (int nf = 0; nf < 4; ++nf) {
      f32x4 s0 = {0.f, 0.f, 0.f, 0.f}, s1 = {0.f, 0.f, 0.f, 0.f};
      const int key = nf * 16 + r;
#pragma unroll
      for (int ks = 0; ks < 4; ++ks) {
        bf16x8 kf = *(const bf16x8*)((const char*)k_lds + key * 256 +
                                     ((ks * 64 + g * 16) ^ ((key & 7) << 4)));
        s0 = MFMA16(qf[0][ks], kf, s0);
        s1 = MFMA16(qf[1][ks], kf, s1);
      }
#pragma unroll
      for (int p = 0; p < 4; ++p) { pv[0][nf][p] = s0[p] * scale; pv[1][nf][p] = s1[p] * scale; }
    }
    __builtin_amdgcn_s_setprio(0);
#pragma unroll
    for (int rg = 0; rg < 2; ++rg) {
      float mnew[4];
#pragma unroll
      for (int p = 0; p < 4; ++p)
        mnew[p] = fmaxf(fmaxf(pv[rg][0][p], pv[rg][1][p]), fmaxf(pv[rg][2][p], pv[rg][3][p]));
#pragma unroll
      for (int m = 1; m < 16; m <<= 1)
#pragma unroll
        for (int p = 0; p < 4; ++p) mnew[p] = fmaxf(mnew[p], __shfl_xor(mnew[p], m, 64));
      float alpha[4], rsum[4];
#pragma unroll
      for (int p = 0; p < 4; ++p) {
        const float mi = fmaxf(m_i[rg][p], mnew[p]);
        alpha[p] = __expf(m_i[rg][p] - mi);
        m_i[rg][p] = mi;
        rsum[p] = 0.f;
      }
#pragma unroll
      for (int nf = 0; nf < 4; ++nf)
#pragma unroll
        for (int p = 0; p < 4; ++p) {
          pv[rg][nf][p] = __expf(pv[rg][nf][p] - m_i[rg][p]);
          rsum[p] += pv[rg][nf][p];
        }
#pragma unroll
      for (int nf = 0; nf < 4; ++nf)
#pragma unroll
        for (int p = 0; p < 4; ++p)
          p_lds[wid][rg][(4 * g + p) * 72 + nf * 16 + r] = (bf16_t)pv[rg][nf][p];
#pragma unroll
      for (int m = 1; m < 16; m <<= 1)
#pragma unroll
        for (int p = 0; p < 4; ++p) rsum[p] += __shfl_xor(rsum[p], m, 64);
#pragma unroll
      for (int p = 0; p < 4; ++p) l_i[rg][p] = l_i[rg][p] * alpha[p] + rsum[p];
#pragma unroll
      for (int nf = 0; nf < 8; ++nf)
#pragma unroll
        for (int p = 0; p < 4; ++p) oacc[rg][nf][p] *= alpha[p];
    }
    bf16x8 pf0[2], pf1[2];
#pragma unroll
    for (int rg = 0; rg < 2; ++rg) {
      pf0[rg] = *(const bf16x8*)&p_lds[wid][rg][r * 72 + 8 * g];
      pf1[rg] = *(const bf16x8*)&p_lds[wid][rg][r * 72 + 32 + 8 * g];
    }
    __builtin_amdgcn_s_setprio(1);
#pragma unroll
    for (int nf = 0; nf < 8; ++nf) {
      const int d = nf * 16 + r;
      bf16x8 vf0 = *(const bf16x8*)((const char*)v_lds + d * 128 +
                                    ((g * 16) ^ ((d & 7) << 4)));
      bf16x8 vf1 = *(const bf16x8*)((const char*)v_lds + d * 128 +
                                    ((64 + g * 16) ^ ((d & 7) << 4)));
#pragma unroll
      for (int rg = 0; rg < 2; ++rg) {
        oacc[rg][nf] = MFMA16(pf0[rg], vf0, oacc[rg][nf]);
        oacc[rg][nf] = MFMA16(pf1[rg], vf1, oacc[rg][nf]);
      }
    }
    __builtin_amdgcn_s_setprio(0);
  }
#pragma unroll
  for (int rg = 0; rg < 2; ++rg)
#pragma unroll
    for (int p = 0; p < 4; ++p) {
      const float inv = 1.f / l_i[rg][p];
      const int rowg = q0 + rg * 16 + 4 * g + p;
#pragma unroll
      for (int nf = 0; nf < 8; ++nf) {
        const int d = nf * 16 + r;
        O[(size_t)rowg * DIMC + h * HD + d] = (bf16_t)(oacc[rg][nf][p] * inv);
      }
    }
}

// ---------------- launch ----------------
extern "C" void kernel_launch(void* const* d_in, const int* in_sizes, int n_in,
                              void* d_out, int out_size, void* d_ws, size_t ws_size,
                              hipStream_t stream) {
  const float* hidden = (const float*)d_in[0];
  const float* fcos   = (const float*)d_in[1];
  const float* fsin   = (const float*)d_in[2];
  const float* Wqkv   = (const float*)d_in[3];
  const float* bqkv   = (const float*)d_in[4];
  const float* wnq    = (const float*)d_in[5];
  const float* wnk    = (const float*)d_in[6];
  const float* Wout   = (const float*)d_in[7];
  const float* bout   = (const float*)d_in[8];
  float* out = (float*)d_out;

  char* ws = (char*)d_ws;
  size_t off = 0;
  auto alloc = [&](size_t bytes) {
    void* p = ws + off;
    off += (bytes + 255) & ~(size_t)255;
    return p;
  };
  bf16_t* X   = (bf16_t*)alloc((size_t)L_C * DIMC * 2);
  bf16_t* WQT = (bf16_t*)alloc((size_t)3 * DIMC * DIMC * 2);
  bf16_t* WOT = (bf16_t*)alloc((size_t)DIMC * DIMC * 2);
  bf16_t* QKV = (bf16_t*)alloc((size_t)L_C * 3 * DIMC * 2);
  bf16_t* Qb  = (bf16_t*)alloc((size_t)L_C * DIMC * 2);
  bf16_t* Kb  = (bf16_t*)alloc((size_t)L_C * DIMC * 2);
  bf16_t* VT  = (bf16_t*)alloc((size_t)L_C * DIMC * 2);
  bf16_t* Ob  = X;  // X dead after gemm1; reuse for attention output

  f32_to_bf16<<<2048, 256, 0, stream>>>(hidden, X, (size_t)L_C * DIMC / 8);
  wtrans<<<dim3(DIMC / 64, 3 * DIMC / 64), 256, 0, stream>>>(Wqkv, WQT, DIMC, 3 * DIMC);
  wtrans<<<dim3(DIMC / 64, DIMC / 64), 256, 0, stream>>>(Wout, WOT, DIMC, DIMC);
  gemm8<1, DIMC><<<dim3(L_C / 256, 3 * DIMC / 256), 512, 0, stream>>>(
      X, WQT, bqkv, QKV, nullptr, L_C, 3 * DIMC);
  norm_rope<<<L_C, 256, 0, stream>>>(QKV, wnq, wnk, fcos, fsin, Qb, Kb);
  v_trans<<<dim3(L_C / 64, NHEADS), 256, 0, stream>>>(QKV, VT);
  attn<<<(L_C / 128) * NHEADS, 256, 0, stream>>>(Qb, Kb, VT, Ob);
  gemm8<0, DIMC><<<dim3(L_C / 256, DIMC / 256), 512, 0, stream>>>(
      Ob, WOT, bout, nullptr, out, L_C, DIMC);
}